// Round 8
// baseline (473.723 us; speedup 1.0000x reference)
//
#include <hip/hip_runtime.h>
#include <hip/hip_bf16.h>
#include <math.h>

#define T_SEQ 2048
#define DM 1024
#define NH 16
#define DH 64
#define CHUNK 64
#define NCHUNK (T_SEQ / CHUNK)   // 32
#define NBLK 512                 // 2 blocks/CU x 256 CUs (coop-guaranteed resident)

typedef __hip_bfloat16 bf16;
typedef __attribute__((ext_vector_type(8))) short short8;
typedef __attribute__((ext_vector_type(4))) short short4v;
typedef __attribute__((ext_vector_type(4))) float f32x4;

static __device__ __forceinline__ short f2b_bits(float f) {
  bf16 t = __float2bfloat16(f);
  short s;
  __builtin_memcpy(&s, &t, 2);
  return s;
}
static __device__ __forceinline__ float b2f(short s) {
  unsigned int u = ((unsigned int)(unsigned short)s) << 16;
  float f;
  __builtin_memcpy(&f, &u, 4);
  return f;
}
// gated ELU+1: elu(x)+1 = x>0 ? x+1 : exp(x)
static __device__ __forceinline__ float gelu1(float raw, float gate, float inv) {
  float x = raw * gate * inv;
  return x > 0.f ? x + 1.f : __expf(x);
}
static __device__ __forceinline__ void gload16(const void* g, void* l) {
  __builtin_amdgcn_global_load_lds((const __attribute__((address_space(1))) void*)g,
                                   (__attribute__((address_space(3))) void*)l, 16, 0, 0);
}

struct P {
  const float *x, *ln_g, *ln_b, *qkv_w, *qkv_b, *gate_w, *gate_b, *proj_w, *proj_b;
  bf16 *xn, *xbf, *wqkv, *wgate, *wproj;
  short *Gb;
  float *ga;
  short *Qb, *Kb, *Vb;
  bf16 *Obuf;
  float *Skv, *Sk;
  float *out;
  int *bar;   // 4 barriers x {arrive, release}; zeroed by memset node pre-launch
};

// Lean single-use grid barrier (CG grid.sync measured ~58us/sync in R7 — 10x too slow).
static __device__ __forceinline__ void gbar(int* bar, int idx) {
  __syncthreads();
  if (threadIdx.x == 0) {
    __threadfence();
    int prev = __hip_atomic_fetch_add(&bar[idx * 2], 1, __ATOMIC_ACQ_REL,
                                      __HIP_MEMORY_SCOPE_AGENT);
    if (prev == NBLK - 1) {
      __hip_atomic_store(&bar[idx * 2 + 1], 1, __ATOMIC_RELEASE,
                         __HIP_MEMORY_SCOPE_AGENT);
    } else {
      while (__hip_atomic_load(&bar[idx * 2 + 1], __ATOMIC_ACQUIRE,
                               __HIP_MEMORY_SCOPE_AGENT) == 0)
        __builtin_amdgcn_s_sleep(8);
    }
    __threadfence();
  }
  __syncthreads();
}

// LDS overlay: per-phase layouts share one 56.8 KB block (2 blocks/CU).
union SH {
  struct { short A[8192]; short B[8192]; } g;                    // 32 KB (gemm1)
  struct { float K[4352]; float V[4352]; } cs;                   // 34.8 KB (csum)
  struct { float Q[4352]; float V[4352]; float KP[4352];
           float denp[1024]; float skp[64]; float den[64]; } at; // 56.8 KB (attn)
  struct { short A[4096]; short B[4096]; } pj;                   // 16 KB (proj)
  float lnred[8];
};

// ---------------------------------------------------------------------------
// Phase 0: grid-stride LayerNorm (+ zero ga) + weight fp32->bf16.
// ---------------------------------------------------------------------------
static __device__ void phase_prep(const P& p, int blk, SH& sh) {
  const int tid = threadIdx.x;
  if (blk < 8) p.ga[blk * 256 + tid] = 0.f;
  for (int row = blk; row < T_SEQ; row += NBLK) {
    const float* xr = p.x + (size_t)row * DM;
    float vals[4];
    float s = 0.f, s2 = 0.f;
#pragma unroll
    for (int i = 0; i < 4; i++) {
      float v = xr[tid + i * 256];
      vals[i] = v;
      s += v;
      s2 += v * v;
    }
#pragma unroll
    for (int m = 1; m < 64; m <<= 1) {
      s += __shfl_xor(s, m, 64);
      s2 += __shfl_xor(s2, m, 64);
    }
    const int wid = tid >> 6;
    if ((tid & 63) == 0) {
      sh.lnred[wid] = s;
      sh.lnred[4 + wid] = s2;
    }
    __syncthreads();
    s = sh.lnred[0] + sh.lnred[1] + sh.lnred[2] + sh.lnred[3];
    s2 = sh.lnred[4] + sh.lnred[5] + sh.lnred[6] + sh.lnred[7];
    __syncthreads();  // WAR guard
    const float mean = s * (1.f / DM);
    const float var = s2 * (1.f / DM) - mean * mean;
    const float rstd = rsqrtf(var + 1e-5f);
#pragma unroll
    for (int i = 0; i < 4; i++) {
      int idx = tid + i * 256;
      float v = (vals[i] - mean) * rstd * p.ln_g[idx] + p.ln_b[idx];
      p.xn[(size_t)row * DM + idx] = __float2bfloat16(v);
      p.xbf[(size_t)row * DM + idx] = __float2bfloat16(vals[i]);
    }
  }
  constexpr int NQ = 3 * DM * DM / 4, NS = DM * DM / 4, N4 = 5 * DM * DM / 4;
  for (int i = blk * 256 + tid; i < N4; i += NBLK * 256) {
    const float* src;
    bf16* dst;
    int j;
    if (i < NQ) { src = p.qkv_w; dst = p.wqkv; j = i; }
    else if (i < NQ + NS) { src = p.gate_w; dst = p.wgate; j = i - NQ; }
    else { src = p.proj_w; dst = p.wproj; j = i - NQ - NS; }
    float4 v = ((const float4*)src)[j];
    short4v sv;
    sv.x = f2b_bits(v.x); sv.y = f2b_bits(v.y); sv.z = f2b_bits(v.z); sv.w = f2b_bits(v.w);
    *(short4v*)&dst[j * 4] = sv;
  }
}

// ---------------------------------------------------------------------------
// Phase 1: fused gate+qkv GEMM, tile 128x128, BK=64.
// ---------------------------------------------------------------------------
static __device__ void phase_gemm1(const P& p, int blk, SH& sh) {
  constexpr int K = 1024;
  const int tid = threadIdx.x;
  const int wid = tid >> 6, lane = tid & 63;
  const int wm = wid >> 1, wn = wid & 1;
  const int lm = lane & 15, quad = lane >> 4;

  const int bx = blk & 15, by = blk >> 4;
  const bool isGate = by < 8;
  const int m0 = bx * 128;
  const int n0 = isGate ? by * 128 : (by - 8) * 128;
  const short* Ag = (const short*)(isGate ? p.xbf : p.xn);
  const short* Wg = (const short*)(isGate ? p.wgate : p.wqkv);

  f32x4 zero = {0.f, 0.f, 0.f, 0.f};
  f32x4 acc[4][4];
#pragma unroll
  for (int i = 0; i < 4; i++)
#pragma unroll
    for (int j = 0; j < 4; j++) acc[i][j] = zero;

  for (int kb = 0; kb < K; kb += 64) {
    __syncthreads();
#pragma unroll
    for (int sec = 0; sec < 2; sec++) {
#pragma unroll
      for (int it = 0; it < 2; it++) {
        const int idx = it * 256 + tid;
        const int row = idx >> 2, seg = (idx & 3) * 8;
        gload16(&Ag[(size_t)(m0 + row) * K + kb + sec * 32 + seg],
                &sh.g.A[sec * 4096 + (it * 256 + wid * 64) * 8]);
        gload16(&Wg[(size_t)(n0 + row) * K + kb + sec * 32 + seg],
                &sh.g.B[sec * 4096 + (it * 256 + wid * 64) * 8]);
      }
    }
    __syncthreads();
#pragma unroll
    for (int sec = 0; sec < 2; sec++) {
      short8 afr[4], bfr[4];
#pragma unroll
      for (int i = 0; i < 4; i++) {
        afr[i] = *(const short8*)&sh.g.A[sec * 4096 + (wm * 64 + i * 16 + lm) * 32 + quad * 8];
        bfr[i] = *(const short8*)&sh.g.B[sec * 4096 + (wn * 64 + i * 16 + lm) * 32 + quad * 8];
      }
#pragma unroll
      for (int i = 0; i < 4; i++)
#pragma unroll
        for (int j = 0; j < 4; j++)
          acc[i][j] = __builtin_amdgcn_mfma_f32_16x16x32_bf16(afr[i], bfr[j], acc[i][j], 0, 0, 0);
    }
  }

  if (isGate) {
    float* red = (float*)sh.g.A;
    __syncthreads();
#pragma unroll
    for (int i = 0; i < 4; i++) {
#pragma unroll
      for (int r = 0; r < 4; r++) {
        const int rowl = wm * 64 + i * 16 + quad * 4 + r;
        const int row = m0 + rowl;
        float rp = 0.f;
#pragma unroll
        for (int j = 0; j < 4; j++) {
          const int col = n0 + wn * 64 + j * 16 + lm;
          float v = acc[i][j][r] + p.gate_b[col];
          float sig = 1.f / (1.f + __expf(-v));
          p.Gb[(size_t)row * DM + col] = f2b_bits(sig);
          rp += sig;
        }
        red[rowl * 32 + wn * 16 + lm] = rp;
      }
    }
    __syncthreads();
    if (tid < 128) {
      float s = 0.f;
#pragma unroll
      for (int t2 = 0; t2 < 32; t2++) s += red[tid * 32 + t2];
      atomicAdd(&p.ga[m0 + tid], s);
    }
  } else {
#pragma unroll
    for (int i = 0; i < 4; i++) {
      const int rbase = m0 + wm * 64 + i * 16 + quad * 4;
#pragma unroll
      for (int j = 0; j < 4; j++) {
        const int col = n0 + wn * 64 + j * 16 + lm;
        const float bval = p.qkv_b[col];
#pragma unroll
        for (int r = 0; r < 4; r++) {
          const int row = rbase + r;
          const short bv = f2b_bits(acc[i][j][r] + bval);
          if (col < DM) {
            const int d = col;
            p.Qb[((size_t)(d >> 6) * T_SEQ + row) * DH + (d & 63)] = bv;
          } else if (col < 2 * DM) {
            const int d = col - DM;
            p.Kb[((size_t)(d >> 6) * T_SEQ + row) * DH + (d & 63)] = bv;
          } else {
            const int d = col - 2 * DM;
            p.Vb[((size_t)(d >> 6) * T_SEQ + row) * DH + (d & 63)] = bv;
          }
        }
      }
    }
  }
}

// ---------------------------------------------------------------------------
// Phase 2: per (h,c) Skv_c = Kg^T V (gating during staging), Sk_c (RAW sums).
// ---------------------------------------------------------------------------
static __device__ void phase_csum(const P& p, int b, SH& sh) {
  constexpr int STR = 68;
  const int h = b >> 5, c = b & 31;
  const int tid = threadIdx.x;
  const int ty = tid >> 4, tx = tid & 15;
  const int d0 = ty * 4, m0 = tx * 4;
  const int t0 = c * CHUNK;
  const size_t cb = ((size_t)h * T_SEQ + t0) * DH;
#pragma unroll
  for (int q = 0; q < 4; q++) {
    int f = q * 256 + tid, row = f >> 4, seg = (f & 15) * 4;
    const int t = t0 + row;
    short4v kr = *(const short4v*)&p.Kb[cb + row * 64 + seg];
    short4v gr = *(const short4v*)&p.Gb[(size_t)t * DM + h * 64 + seg];
    short4v vr = *(const short4v*)&p.Vb[cb + row * 64 + seg];
    const float inv = 1.f / (p.ga[t] * (1.f / DM) + 1e-5f);
    f32x4 kgv, vv;
#pragma unroll
    for (int e = 0; e < 4; e++) {
      kgv[e] = gelu1(b2f(kr[e]), b2f(gr[e]), inv);
      vv[e] = b2f(vr[e]);
    }
    *(f32x4*)&sh.cs.K[row * STR + seg] = kgv;
    *(f32x4*)&sh.cs.V[row * STR + seg] = vv;
  }
  __syncthreads();
  float acc[4][4] = {};
#pragma unroll 4
  for (int s = 0; s < 64; s++) {
    f32x4 kf = *(const f32x4*)&sh.cs.K[s * STR + d0];
    f32x4 vf = *(const f32x4*)&sh.cs.V[s * STR + m0];
#pragma unroll
    for (int i = 0; i < 4; i++)
#pragma unroll
      for (int j = 0; j < 4; j++) acc[i][j] += kf[i] * vf[j];
  }
  float* outp = p.Skv + (size_t)b * 4096;
#pragma unroll
  for (int i = 0; i < 4; i++) {
    f32x4 o = {acc[i][0], acc[i][1], acc[i][2], acc[i][3]};
    *(f32x4*)&outp[(d0 + i) * 64 + m0] = o;
  }
  if (tid < 64) {
    float ss = 0.f;
#pragma unroll 4
    for (int s = 0; s < 64; s++) ss += sh.cs.K[s * STR + tid];
    p.Sk[b * 64 + tid] = ss;
  }
  __syncthreads();  // protect LDS before overlay
}

// ---------------------------------------------------------------------------
// Phase 3: attn with INLINE prefix scan: P = sum of Skv chunks 0..c-1 (regs),
// skp likewise. Then accO = Q.P ; S = Q K^T (causal) ; accO += S.V ;
// den = q.skp + rowsum(S).
// ---------------------------------------------------------------------------
static __device__ void phase_attn(const P& p, int b, SH& sh) {
  constexpr int STR = 68;
  const int h = b >> 5, c = b & 31;
  const int tid = threadIdx.x;
  const int ty = tid >> 4, tx = tid & 15;
  const int r0 = ty * 4, c0 = tx * 4, m0 = tx * 4;
  const int t0 = c * CHUNK;
  const size_t cb = ((size_t)h * T_SEQ + t0) * DH;

  // K prefetch (raw + gate + inv) into registers; consumed in phase-2 of attn
  short4v kreg[4], greg[4];
  float ireg[4];
#pragma unroll
  for (int q = 0; q < 4; q++) {
    int f = q * 256 + tid, row = f >> 4, seg = (f & 15) * 4;
    kreg[q] = *(const short4v*)&p.Kb[cb + row * 64 + seg];
    greg[q] = *(const short4v*)&p.Gb[(size_t)(t0 + row) * DM + h * 64 + seg];
    ireg[q] = 1.f / (p.ga[t0 + row] * (1.f / DM) + 1e-5f);
  }
  // stage gated Q, V
#pragma unroll
  for (int q = 0; q < 4; q++) {
    int f = q * 256 + tid, row = f >> 4, seg = (f & 15) * 4;
    short4v qr = *(const short4v*)&p.Qb[cb + row * 64 + seg];
    short4v gq = *(const short4v*)&p.Gb[(size_t)(t0 + row) * DM + h * 64 + seg];
    short4v vr = *(const short4v*)&p.Vb[cb + row * 64 + seg];
    const float inv = 1.f / (p.ga[t0 + row] * (1.f / DM) + 1e-5f);
    f32x4 qgv, vv;
#pragma unroll
    for (int e = 0; e < 4; e++) {
      qgv[e] = gelu1(b2f(qr[e]), b2f(gq[e]), inv);
      vv[e] = b2f(vr[e]);
    }
    *(f32x4*)&sh.at.Q[row * STR + seg] = qgv;
    *(f32x4*)&sh.at.V[row * STR + seg] = vv;
  }
  // inline prefix: P = sum_{cc<c} Skv[h,cc], in registers (coalesced float4)
  f32x4 preg[4];
#pragma unroll
  for (int g = 0; g < 4; g++) preg[g] = {0.f, 0.f, 0.f, 0.f};
  for (int cc = 0; cc < c; cc++) {
    const float* Pc = p.Skv + ((size_t)(h * NCHUNK + cc)) * 4096;
#pragma unroll
    for (int g = 0; g < 4; g++) preg[g] += *(const f32x4*)&Pc[g * 1024 + tid * 4];
  }
  if (tid < 64) {
    float skpv = 0.f;
    for (int cc = 0; cc < c; cc++) skpv += p.Sk[(h * NCHUNK + cc) * 64 + tid];
    sh.at.skp[tid] = skpv;
  }
  // write P to KP LDS: element E = g*1024 + tid*4 -> row=E>>6, seg=E&63
#pragma unroll
  for (int g = 0; g < 4; g++) {
    const int E = g * 1024 + tid * 4;
    *(f32x4*)&sh.at.KP[(E >> 6) * STR + (E & 63)] = preg[g];
  }
  __syncthreads();  // B1

  if (tid < 64) {
    float s = 1e-5f;
#pragma unroll 4
    for (int d = 0; d < 64; d++) s += sh.at.Q[tid * STR + d] * sh.at.skp[d];
    sh.at.den[tid] = s;
  }

  float accO[4][4] = {};
#pragma unroll 2
  for (int d0 = 0; d0 < 64; d0 += 4) {
    f32x4 qf[4], pf[4];
#pragma unroll
    for (int i = 0; i < 4; i++) qf[i] = *(const f32x4*)&sh.at.Q[(r0 + i) * STR + d0];
#pragma unroll
    for (int dd = 0; dd < 4; dd++) pf[dd] = *(const f32x4*)&sh.at.KP[(d0 + dd) * STR + m0];
#pragma unroll
    for (int i = 0; i < 4; i++)
#pragma unroll
      for (int j = 0; j < 4; j++)
        accO[i][j] += qf[i][0] * pf[0][j] + qf[i][1] * pf[1][j] +
                      qf[i][2] * pf[2][j] + qf[i][3] * pf[3][j];
  }
  __syncthreads();  // B2: P reads done -> region becomes gated K
#pragma unroll
  for (int q = 0; q < 4; q++) {
    int f = q * 256 + tid, row = f >> 4, seg = (f & 15) * 4;
    f32x4 kgv;
#pragma unroll
    for (int e = 0; e < 4; e++) kgv[e] = gelu1(b2f(kreg[q][e]), b2f(greg[q][e]), ireg[q]);
    *(f32x4*)&sh.at.KP[row * STR + seg] = kgv;
  }
  __syncthreads();  // B3

  float accS[4][4] = {};
#pragma unroll 2
  for (int d0 = 0; d0 < 64; d0 += 4) {
    f32x4 qf[4], kf[4];
#pragma unroll
    for (int i = 0; i < 4; i++) qf[i] = *(const f32x4*)&sh.at.Q[(r0 + i) * STR + d0];
#pragma unroll
    for (int j = 0; j < 4; j++) kf[j] = *(const f32x4*)&sh.at.KP[(c0 + j) * STR + d0];
#pragma unroll
    for (int i = 0; i < 4; i++)
#pragma unroll
      for (int j = 0; j < 4; j++)
        accS[i][j] += qf[i][0] * kf[j][0] + qf[i][1] * kf[j][1] +
                      qf[i][2] * kf[j][2] + qf[i][3] * kf[j][3];
  }
  float dp[4];
#pragma unroll
  for (int i = 0; i < 4; i++) {
    dp[i] = 0.f;
#pragma unroll
    for (int j = 0; j < 4; j++) {
      float v = (c0 + j) <= (r0 + i) ? accS[i][j] : 0.f;
      accS[i][j] = v;
      dp[i] += v;
    }
  }
  __syncthreads();  // B4
#pragma unroll
  for (int i = 0; i < 4; i++) {
    f32x4 sv = {accS[i][0], accS[i][1], accS[i][2], accS[i][3]};
    *(f32x4*)&sh.at.Q[(r0 + i) * STR + c0] = sv;
    sh.at.denp[(r0 + i) * 16 + tx] = dp[i];
  }
  __syncthreads();  // B5
  if (tid < 64) {
    float s = sh.at.den[tid];
#pragma unroll
    for (int t = 0; t < 16; t++) s += sh.at.denp[tid * 16 + t];
    sh.at.den[tid] = s;
  }

#pragma unroll 2
  for (int c4 = 0; c4 < 64; c4 += 4) {
    f32x4 sf[4], vf[4];
#pragma unroll
    for (int i = 0; i < 4; i++) sf[i] = *(const f32x4*)&sh.at.Q[(r0 + i) * STR + c4];
#pragma unroll
    for (int cc = 0; cc < 4; cc++) vf[cc] = *(const f32x4*)&sh.at.V[(c4 + cc) * STR + m0];
#pragma unroll
    for (int i = 0; i < 4; i++)
#pragma unroll
      for (int j = 0; j < 4; j++)
        accO[i][j] += sf[i][0] * vf[0][j] + sf[i][1] * vf[1][j] +
                      sf[i][2] * vf[2][j] + sf[i][3] * vf[3][j];
  }
  __syncthreads();  // B6

#pragma unroll
  for (int i = 0; i < 4; i++) {
    const float inv = 1.f / sh.at.den[r0 + i];
    short4v ov;
#pragma unroll
    for (int j = 0; j < 4; j++) ov[j] = f2b_bits(accO[i][j] * inv);
    *(short4v*)&p.Obuf[(size_t)(t0 + r0 + i) * DM + h * 64 + m0] = ov;
  }
  __syncthreads();  // protect LDS before overlay
}

// ---------------------------------------------------------------------------
// Phase 4: proj GEMM, 64x64 tiles, BK=64, 512 tiles.
// ---------------------------------------------------------------------------
static __device__ void phase_proj(const P& p, int blk, SH& sh) {
  constexpr int K = 1024;
  const int tid = threadIdx.x;
  const int wid = tid >> 6, lane = tid & 63;
  const int wm = wid >> 1, wn = wid & 1;
  const int lm = lane & 15, quad = lane >> 4;

  const int m0 = (blk & 31) * 64;
  const int n0 = (blk >> 5) * 64;
  const short* Ag = (const short*)p.Obuf;
  const short* Wg = (const short*)p.wproj;

  f32x4 zero = {0.f, 0.f, 0.f, 0.f};
  f32x4 acc[2][2];
#pragma unroll
  for (int i = 0; i < 2; i++)
#pragma unroll
    for (int j = 0; j < 2; j++) acc[i][j] = zero;

  for (int kb = 0; kb < K; kb += 64) {
    __syncthreads();
#pragma unroll
    for (int sec = 0; sec < 2; sec++) {
      const int row = tid >> 2, seg = (tid & 3) * 8;
      gload16(&Ag[(size_t)(m0 + row) * K + kb + sec * 32 + seg],
              &sh.pj.A[sec * 2048 + wid * 512]);
      gload16(&Wg[(size_t)(n0 + row) * K + kb + sec * 32 + seg],
              &sh.pj.B[sec * 2048 + wid * 512]);
    }
    __syncthreads();
#pragma unroll
    for (int sec = 0; sec < 2; sec++) {
      short8 afr[2], bfr[2];
#pragma unroll
      for (int i = 0; i < 2; i++)
        afr[i] = *(const short8*)&sh.pj.A[sec * 2048 + (wm * 32 + i * 16 + lm) * 32 + quad * 8];
#pragma unroll
      for (int j = 0; j < 2; j++)
        bfr[j] = *(const short8*)&sh.pj.B[sec * 2048 + (wn * 32 + j * 16 + lm) * 32 + quad * 8];
#pragma unroll
      for (int i = 0; i < 2; i++)
#pragma unroll
        for (int j = 0; j < 2; j++)
          acc[i][j] = __builtin_amdgcn_mfma_f32_16x16x32_bf16(afr[i], bfr[j], acc[i][j], 0, 0, 0);
    }
  }
#pragma unroll
  for (int i = 0; i < 2; i++) {
    const int rbase = m0 + wm * 32 + i * 16 + quad * 4;
#pragma unroll
    for (int j = 0; j < 2; j++) {
      const int col = n0 + wn * 32 + j * 16 + lm;
      const float bval = p.proj_b[col];
#pragma unroll
      for (int r = 0; r < 4; r++)
        p.out[(size_t)(rbase + r) * DM + col] = acc[i][j][r] + bval;
    }
  }
}

// ---------------------------------------------------------------------------
// Mega-kernel with hand-rolled grid barriers (4 sync points).
// ---------------------------------------------------------------------------
__global__ __launch_bounds__(256, 2) void mega_kernel(P p) {
  __shared__ __align__(16) SH sh;
  const int blk = blockIdx.x;
  phase_prep(p, blk, sh);
  gbar(p.bar, 0);
  phase_gemm1(p, blk, sh);
  gbar(p.bar, 1);
  phase_csum(p, blk, sh);
  gbar(p.bar, 2);
  phase_attn(p, blk, sh);
  gbar(p.bar, 3);
  phase_proj(p, blk, sh);
}

// Fallback: identical phases as 5 separate launches.
__global__ __launch_bounds__(256) void k_prep(P p)  { __shared__ __align__(16) SH sh; phase_prep(p, blockIdx.x, sh); }
__global__ __launch_bounds__(256) void k_gemm1(P p) { __shared__ __align__(16) SH sh; phase_gemm1(p, blockIdx.x, sh); }
__global__ __launch_bounds__(256) void k_csum(P p)  { __shared__ __align__(16) SH sh; phase_csum(p, blockIdx.x, sh); }
__global__ __launch_bounds__(256) void k_attn(P p)  { __shared__ __align__(16) SH sh; phase_attn(p, blockIdx.x, sh); }
__global__ __launch_bounds__(256) void k_proj(P p)  { __shared__ __align__(16) SH sh; phase_proj(p, blockIdx.x, sh); }

// ---------------------------------------------------------------------------
extern "C" void kernel_launch(void* const* d_in, const int* in_sizes, int n_in,
                              void* d_out, int out_size, void* d_ws, size_t ws_size,
                              hipStream_t stream) {
  (void)in_sizes; (void)n_in; (void)out_size; (void)ws_size;
  char* ws = (char*)d_ws;
  size_t off = 0;
  auto alloc = [&](size_t bytes) {
    void* pp = ws + off;
    off += (bytes + 255) & ~(size_t)255;
    return pp;
  };
  P p;
  p.x      = (const float*)d_in[0];
  p.ln_g   = (const float*)d_in[1];
  p.ln_b   = (const float*)d_in[2];
  p.qkv_w  = (const float*)d_in[3];
  p.qkv_b  = (const float*)d_in[4];
  p.gate_w = (const float*)d_in[5];
  p.gate_b = (const float*)d_in[6];
  p.proj_w = (const float*)d_in[7];
  p.proj_b = (const float*)d_in[8];
  p.out    = (float*)d_out;
  p.xn     = (bf16*)alloc((size_t)T_SEQ * DM * 2);
  p.xbf    = (bf16*)alloc((size_t)T_SEQ * DM * 2);
  p.wqkv   = (bf16*)alloc((size_t)3 * DM * DM * 2);
  p.wgate  = (bf16*)alloc((size_t)DM * DM * 2);
  p.wproj  = (bf16*)alloc((size_t)DM * DM * 2);
  p.Gb     = (short*)alloc((size_t)T_SEQ * DM * 2);
  p.ga     = (float*)alloc((size_t)T_SEQ * 4);
  p.Qb     = (short*)alloc((size_t)T_SEQ * DM * 2);
  p.Kb     = (short*)alloc((size_t)T_SEQ * DM * 2);
  p.Vb     = (short*)alloc((size_t)T_SEQ * DM * 2);
  p.Obuf   = (bf16*)alloc((size_t)T_SEQ * DM * 2);
  p.Skv    = (float*)alloc((size_t)NH * NCHUNK * 4096 * 4);
  p.Sk     = (float*)alloc((size_t)NH * NCHUNK * 64 * 4);
  p.bar    = (int*)alloc(8 * sizeof(int));

  // zero the barrier slots (ws is poisoned 0xAA before every replay)
  hipMemsetAsync(p.bar, 0, 8 * sizeof(int), stream);

  void* args[] = {&p};
  hipError_t e = hipLaunchCooperativeKernel((void*)mega_kernel, dim3(NBLK), dim3(256),
                                            args, 0, stream);
  if (e != hipSuccess) {
    (void)hipGetLastError();  // clear
    k_prep<<<NBLK, 256, 0, stream>>>(p);
    k_gemm1<<<NBLK, 256, 0, stream>>>(p);
    k_csum<<<NBLK, 256, 0, stream>>>(p);
    k_attn<<<NBLK, 256, 0, stream>>>(p);
    k_proj<<<NBLK, 256, 0, stream>>>(p);
  }
}

// Round 9
// 170.276 us; speedup vs baseline: 2.7821x; 2.7821x over previous
//
#include <hip/hip_runtime.h>
#include <hip/hip_bf16.h>
#include <math.h>

#define T_SEQ 2048
#define DM 1024
#define NH 16
#define DH 64
#define CHUNK 64
#define NCHUNK (T_SEQ / CHUNK)   // 32

typedef __hip_bfloat16 bf16;
typedef __attribute__((ext_vector_type(8))) short short8;
typedef __attribute__((ext_vector_type(4))) short short4v;
typedef __attribute__((ext_vector_type(4))) float f32x4;

static __device__ __forceinline__ short f2b_bits(float f) {
  bf16 t = __float2bfloat16(f);
  short s;
  __builtin_memcpy(&s, &t, 2);
  return s;
}
static __device__ __forceinline__ float b2f(short s) {
  unsigned int u = ((unsigned int)(unsigned short)s) << 16;
  float f;
  __builtin_memcpy(&f, &u, 4);
  return f;
}
// gated ELU+1: elu(x)+1 = x>0 ? x+1 : exp(x)
static __device__ __forceinline__ float gelu1(float raw, float gate, float inv) {
  float x = raw * gate * inv;
  return x > 0.f ? x + 1.f : __expf(x);
}
static __device__ __forceinline__ void gload16(const void* g, void* l) {
  __builtin_amdgcn_global_load_lds((const __attribute__((address_space(1))) void*)g,
                                   (__attribute__((address_space(3))) void*)l, 16, 0, 0);
}

// ---------------------------------------------------------------------------
// prep: blocks 0..2047 = LayerNorm rows (blocks 0..7 also zero gate_accum);
//       blocks 2048..  = fp32->bf16 weight conversion (qkv|gate|proj).
// ---------------------------------------------------------------------------
#define PREP_WBLOCKS (5 * DM * DM / 4 / 256)   // 5120
__global__ __launch_bounds__(256) void prep_kernel(
    const float* __restrict__ x, const float* __restrict__ g,
    const float* __restrict__ b, const float* __restrict__ qkv_w,
    const float* __restrict__ gate_w, const float* __restrict__ proj_w,
    bf16* __restrict__ xn, bf16* __restrict__ xbf,
    bf16* __restrict__ wqkv, bf16* __restrict__ wgate, bf16* __restrict__ wproj,
    float* __restrict__ gate_accum) {
  const int blk = blockIdx.x;
  if (blk < T_SEQ) {
    const int row = blk;
    if (row < 8) gate_accum[row * 256 + threadIdx.x] = 0.f;
    const float* xr = x + (size_t)row * DM;
    float vals[4];
    float s = 0.f, s2 = 0.f;
#pragma unroll
    for (int i = 0; i < 4; i++) {
      float v = xr[threadIdx.x + i * 256];
      vals[i] = v;
      s += v;
      s2 += v * v;
    }
#pragma unroll
    for (int m = 1; m < 64; m <<= 1) {
      s += __shfl_xor(s, m, 64);
      s2 += __shfl_xor(s2, m, 64);
    }
    __shared__ float red[8];
    const int wid = threadIdx.x >> 6;
    if ((threadIdx.x & 63) == 0) {
      red[wid] = s;
      red[4 + wid] = s2;
    }
    __syncthreads();
    s = red[0] + red[1] + red[2] + red[3];
    s2 = red[4] + red[5] + red[6] + red[7];
    const float mean = s * (1.f / DM);
    const float var = s2 * (1.f / DM) - mean * mean;
    const float rstd = rsqrtf(var + 1e-5f);
#pragma unroll
    for (int i = 0; i < 4; i++) {
      int idx = threadIdx.x + i * 256;
      float v = (vals[i] - mean) * rstd * g[idx] + b[idx];
      xn[(size_t)row * DM + idx] = __float2bfloat16(v);
      xbf[(size_t)row * DM + idx] = __float2bfloat16(vals[i]);
    }
  } else {
    constexpr int NQ = 3 * DM * DM / 4, NS = DM * DM / 4;
    int i = (blk - T_SEQ) * 256 + threadIdx.x;
    const float* src;
    bf16* dst;
    int j;
    if (i < NQ) { src = qkv_w; dst = wqkv; j = i; }
    else if (i < NQ + NS) { src = gate_w; dst = wgate; j = i - NQ; }
    else { src = proj_w; dst = wproj; j = i - NQ - NS; }
    float4 v = ((const float4*)src)[j];
    short4v sv;
    sv.x = f2b_bits(v.x); sv.y = f2b_bits(v.y); sv.z = f2b_bits(v.z); sv.w = f2b_bits(v.w);
    *(short4v*)&dst[j * 4] = sv;
  }
}

// ---------------------------------------------------------------------------
// Fused gate+qkv GEMM, tile 128x128, BK=64.
// grid (16, 32): y<8 -> gate: sigmoid -> Gb (bf16) + row-sum atomics into ga;
//                y>=8 -> qkv: RAW biased q,k,v scatter [H][T][DH] bf16.
// ---------------------------------------------------------------------------
__global__ __launch_bounds__(256) void gemm_gateqkv(
    const bf16* __restrict__ xbf, const bf16* __restrict__ xn,
    const bf16* __restrict__ wg, const bf16* __restrict__ wq,
    const float* __restrict__ gate_b, const float* __restrict__ qkv_b,
    short* __restrict__ Gb, float* __restrict__ gate_accum,
    short* __restrict__ Qb, short* __restrict__ Kb, short* __restrict__ Vb) {
  constexpr int K = 1024;
  __shared__ __align__(16) short As[2 * 128 * 32];
  __shared__ __align__(16) short Bs[2 * 128 * 32];

  const int tid = threadIdx.x;
  const int wid = tid >> 6, lane = tid & 63;
  const int wm = wid >> 1, wn = wid & 1;
  const int lm = lane & 15, quad = lane >> 4;

  const bool isGate = blockIdx.y < 8;
  const int m0 = blockIdx.x * 128;
  const int n0 = isGate ? blockIdx.y * 128 : (blockIdx.y - 8) * 128;
  const short* Ag = (const short*)(isGate ? xbf : xn);
  const short* Wg = (const short*)(isGate ? wg : wq);

  f32x4 zero = {0.f, 0.f, 0.f, 0.f};
  f32x4 acc[4][4];
#pragma unroll
  for (int i = 0; i < 4; i++)
#pragma unroll
    for (int j = 0; j < 4; j++) acc[i][j] = zero;

  for (int kb = 0; kb < K; kb += 64) {
    __syncthreads();
#pragma unroll
    for (int sec = 0; sec < 2; sec++) {
#pragma unroll
      for (int it = 0; it < 2; it++) {
        const int idx = it * 256 + tid;
        const int row = idx >> 2, seg = (idx & 3) * 8;
        gload16(&Ag[(size_t)(m0 + row) * K + kb + sec * 32 + seg],
                &As[sec * 4096 + (it * 256 + wid * 64) * 8]);
        gload16(&Wg[(size_t)(n0 + row) * K + kb + sec * 32 + seg],
                &Bs[sec * 4096 + (it * 256 + wid * 64) * 8]);
      }
    }
    __syncthreads();
#pragma unroll
    for (int sec = 0; sec < 2; sec++) {
      short8 afr[4], bfr[4];
#pragma unroll
      for (int i = 0; i < 4; i++) {
        afr[i] = *(const short8*)&As[sec * 4096 + (wm * 64 + i * 16 + lm) * 32 + quad * 8];
        bfr[i] = *(const short8*)&Bs[sec * 4096 + (wn * 64 + i * 16 + lm) * 32 + quad * 8];
      }
#pragma unroll
      for (int i = 0; i < 4; i++)
#pragma unroll
        for (int j = 0; j < 4; j++)
          acc[i][j] = __builtin_amdgcn_mfma_f32_16x16x32_bf16(afr[i], bfr[j], acc[i][j], 0, 0, 0);
    }
  }

  // epilogue: C/D layout col = lane&15, row = quad*4 + r
  if (isGate) {
    float* red = (float*)As;   // 128 rows x 32 slots = 16 KB
    __syncthreads();           // MFMA LDS reads done -> safe to reuse As
#pragma unroll
    for (int i = 0; i < 4; i++) {
#pragma unroll
      for (int r = 0; r < 4; r++) {
        const int rowl = wm * 64 + i * 16 + quad * 4 + r;
        const int row = m0 + rowl;
        float rp = 0.f;
#pragma unroll
        for (int j = 0; j < 4; j++) {
          const int col = n0 + wn * 64 + j * 16 + lm;
          float v = acc[i][j][r] + gate_b[col];
          float sig = 1.f / (1.f + __expf(-v));
          Gb[(size_t)row * DM + col] = f2b_bits(sig);
          rp += sig;
        }
        red[rowl * 32 + wn * 16 + lm] = rp;
      }
    }
    __syncthreads();
    if (tid < 128) {
      float s = 0.f;
#pragma unroll
      for (int t2 = 0; t2 < 32; t2++) s += red[tid * 32 + t2];
      atomicAdd(&gate_accum[m0 + tid], s);
    }
  } else {
#pragma unroll
    for (int i = 0; i < 4; i++) {
      const int rbase = m0 + wm * 64 + i * 16 + quad * 4;
#pragma unroll
      for (int j = 0; j < 4; j++) {
        const int col = n0 + wn * 64 + j * 16 + lm;
        const float bval = qkv_b[col];
#pragma unroll
        for (int r = 0; r < 4; r++) {
          const int row = rbase + r;
          const short bv = f2b_bits(acc[i][j][r] + bval);
          if (col < DM) {
            const int d = col;
            Qb[((size_t)(d >> 6) * T_SEQ + row) * DH + (d & 63)] = bv;
          } else if (col < 2 * DM) {
            const int d = col - DM;
            Kb[((size_t)(d >> 6) * T_SEQ + row) * DH + (d & 63)] = bv;
          } else {
            const int d = col - 2 * DM;
            Vb[((size_t)(d >> 6) * T_SEQ + row) * DH + (d & 63)] = bv;
          }
        }
      }
    }
  }
}

// ---------------------------------------------------------------------------
// Pass A: per (h,c) RAW chunk sums Skv_c = Kg^T V, Sk_c = col sums of Kg
// (gating+ELU applied during staging).
// ---------------------------------------------------------------------------
__global__ __launch_bounds__(256, 2) void chunk_sum_mm(const short* __restrict__ Kb,
                                                       const short* __restrict__ Gb,
                                                       const float* __restrict__ ga,
                                                       const short* __restrict__ Vb,
                                                       float* __restrict__ Skv,
                                                       float* __restrict__ Sk) {
  constexpr int STR = 68;
  __shared__ __align__(16) float Ks2[64 * STR];
  __shared__ __align__(16) float Vs2[64 * STR];
  const int b = blockIdx.x;
  const int h = b >> 5, c = b & 31;
  const int tid = threadIdx.x;
  const int ty = tid >> 4, tx = tid & 15;
  const int d0 = ty * 4, m0 = tx * 4;
  const int t0 = c * CHUNK;
  const size_t cb = ((size_t)h * T_SEQ + t0) * DH;
#pragma unroll
  for (int p = 0; p < 4; p++) {
    int f = p * 256 + tid, row = f >> 4, seg = (f & 15) * 4;
    const int t = t0 + row;
    short4v kr = *(const short4v*)&Kb[cb + row * 64 + seg];
    short4v gr = *(const short4v*)&Gb[(size_t)t * DM + h * 64 + seg];
    short4v vr = *(const short4v*)&Vb[cb + row * 64 + seg];
    const float inv = 1.f / (ga[t] * (1.f / DM) + 1e-5f);
    f32x4 kgv, vv;
#pragma unroll
    for (int e = 0; e < 4; e++) {
      kgv[e] = gelu1(b2f(kr[e]), b2f(gr[e]), inv);
      vv[e] = b2f(vr[e]);
    }
    *(f32x4*)&Ks2[row * STR + seg] = kgv;
    *(f32x4*)&Vs2[row * STR + seg] = vv;
  }
  __syncthreads();
  float acc[4][4] = {};
#pragma unroll 4
  for (int s = 0; s < 64; s++) {
    f32x4 kf = *(const f32x4*)&Ks2[s * STR + d0];
    f32x4 vf = *(const f32x4*)&Vs2[s * STR + m0];
#pragma unroll
    for (int i = 0; i < 4; i++)
#pragma unroll
      for (int j = 0; j < 4; j++) acc[i][j] += kf[i] * vf[j];
  }
  float* outp = Skv + (size_t)b * 4096;
#pragma unroll
  for (int i = 0; i < 4; i++) {
    f32x4 o = {acc[i][0], acc[i][1], acc[i][2], acc[i][3]};
    *(f32x4*)&outp[(d0 + i) * 64 + m0] = o;
  }
  if (tid < 64) {
    float ss = 0.f;
#pragma unroll 4
    for (int s = 0; s < 64; s++) ss += Ks2[s * STR + tid];
    Sk[b * 64 + tid] = ss;
  }
}

// ---------------------------------------------------------------------------
// Pass B: attn with INLINE prefix (reads RAW Skv/Sk of chunks < c; no scan
// kernel). accO = Q.P ; S = Q K^T (causal) ; accO += S.V ; den = q.skp + rowsum(S).
// ---------------------------------------------------------------------------
__global__ __launch_bounds__(256, 2) void attn_mm(const short* __restrict__ Qb,
                                                  const short* __restrict__ Kb,
                                                  const short* __restrict__ Gb,
                                                  const float* __restrict__ ga,
                                                  const short* __restrict__ Vb,
                                                  const float* __restrict__ Skv,
                                                  const float* __restrict__ Sk,
                                                  bf16* __restrict__ O) {
  constexpr int STR = 68;
  __shared__ __align__(16) float Qs[64 * STR];   // gated Q, later S
  __shared__ __align__(16) float Vs[64 * STR];
  __shared__ __align__(16) float KPs[64 * STR];  // P phase 1, gated K phase 2
  __shared__ float denp[64 * 16];
  __shared__ float skp[64];
  __shared__ float den[64];
  const int b = blockIdx.x;
  const int h = b >> 5, c = b & 31;
  const int tid = threadIdx.x;
  const int ty = tid >> 4, tx = tid & 15;
  const int r0 = ty * 4, c0 = tx * 4, m0 = tx * 4;
  const int t0 = c * CHUNK;
  const size_t cb = ((size_t)h * T_SEQ + t0) * DH;

  // K prefetch (raw + gate + inv) into registers; consumed in phase 2
  short4v kreg[4], greg[4];
  float ireg[4];
#pragma unroll
  for (int q = 0; q < 4; q++) {
    int f = q * 256 + tid, row = f >> 4, seg = (f & 15) * 4;
    kreg[q] = *(const short4v*)&Kb[cb + row * 64 + seg];
    greg[q] = *(const short4v*)&Gb[(size_t)(t0 + row) * DM + h * 64 + seg];
    ireg[q] = 1.f / (ga[t0 + row] * (1.f / DM) + 1e-5f);
  }
  // stage gated Q, V
#pragma unroll
  for (int q = 0; q < 4; q++) {
    int f = q * 256 + tid, row = f >> 4, seg = (f & 15) * 4;
    short4v qr = *(const short4v*)&Qb[cb + row * 64 + seg];
    short4v gq = *(const short4v*)&Gb[(size_t)(t0 + row) * DM + h * 64 + seg];
    short4v vr = *(const short4v*)&Vb[cb + row * 64 + seg];
    const float inv = 1.f / (ga[t0 + row] * (1.f / DM) + 1e-5f);
    f32x4 qgv, vv;
#pragma unroll
    for (int e = 0; e < 4; e++) {
      qgv[e] = gelu1(b2f(qr[e]), b2f(gq[e]), inv);
      vv[e] = b2f(vr[e]);
    }
    *(f32x4*)&Qs[row * STR + seg] = qgv;
    *(f32x4*)&Vs[row * STR + seg] = vv;
  }
  // inline prefix: P = sum_{cc<c} Skv[h,cc] in registers (coalesced float4)
  f32x4 preg[4];
#pragma unroll
  for (int g = 0; g < 4; g++) preg[g] = {0.f, 0.f, 0.f, 0.f};
  for (int cc = 0; cc < c; cc++) {
    const float* Pc = Skv + ((size_t)(h * NCHUNK + cc)) * 4096;
#pragma unroll
    for (int g = 0; g < 4; g++) preg[g] += *(const f32x4*)&Pc[g * 1024 + tid * 4];
  }
  if (tid < 64) {
    float skpv = 0.f;
    for (int cc = 0; cc < c; cc++) skpv += Sk[(h * NCHUNK + cc) * 64 + tid];
    skp[tid] = skpv;
  }
  // write P to KP LDS: element E = g*1024 + tid*4 -> row=E>>6, col=E&63
#pragma unroll
  for (int g = 0; g < 4; g++) {
    const int E = g * 1024 + tid * 4;
    *(f32x4*)&KPs[(E >> 6) * STR + (E & 63)] = preg[g];
  }
  __syncthreads();  // B1

  if (tid < 64) {
    float s = 1e-5f;
#pragma unroll 4
    for (int d = 0; d < 64; d++) s += Qs[tid * STR + d] * skp[d];
    den[tid] = s;
  }

  float accO[4][4] = {};
#pragma unroll 2
  for (int d0 = 0; d0 < 64; d0 += 4) {
    f32x4 qf[4], pf[4];
#pragma unroll
    for (int i = 0; i < 4; i++) qf[i] = *(const f32x4*)&Qs[(r0 + i) * STR + d0];
#pragma unroll
    for (int dd = 0; dd < 4; dd++) pf[dd] = *(const f32x4*)&KPs[(d0 + dd) * STR + m0];
#pragma unroll
    for (int i = 0; i < 4; i++)
#pragma unroll
      for (int j = 0; j < 4; j++)
        accO[i][j] += qf[i][0] * pf[0][j] + qf[i][1] * pf[1][j] +
                      qf[i][2] * pf[2][j] + qf[i][3] * pf[3][j];
  }
  __syncthreads();  // B2: P reads done -> region becomes gated K
#pragma unroll
  for (int q = 0; q < 4; q++) {
    int f = q * 256 + tid, row = f >> 4, seg = (f & 15) * 4;
    f32x4 kgv;
#pragma unroll
    for (int e = 0; e < 4; e++) kgv[e] = gelu1(b2f(kreg[q][e]), b2f(greg[q][e]), ireg[q]);
    *(f32x4*)&KPs[row * STR + seg] = kgv;
  }
  __syncthreads();  // B3

  float accS[4][4] = {};
#pragma unroll 2
  for (int d0 = 0; d0 < 64; d0 += 4) {
    f32x4 qf[4], kf[4];
#pragma unroll
    for (int i = 0; i < 4; i++) qf[i] = *(const f32x4*)&Qs[(r0 + i) * STR + d0];
#pragma unroll
    for (int j = 0; j < 4; j++) kf[j] = *(const f32x4*)&KPs[(c0 + j) * STR + d0];
#pragma unroll
    for (int i = 0; i < 4; i++)
#pragma unroll
      for (int j = 0; j < 4; j++)
        accS[i][j] += qf[i][0] * kf[j][0] + qf[i][1] * kf[j][1] +
                      qf[i][2] * kf[j][2] + qf[i][3] * kf[j][3];
  }
  float dp[4];
#pragma unroll
  for (int i = 0; i < 4; i++) {
    dp[i] = 0.f;
#pragma unroll
    for (int j = 0; j < 4; j++) {
      float v = (c0 + j) <= (r0 + i) ? accS[i][j] : 0.f;
      accS[i][j] = v;
      dp[i] += v;
    }
  }
  __syncthreads();  // B4
#pragma unroll
  for (int i = 0; i < 4; i++) {
    f32x4 sv = {accS[i][0], accS[i][1], accS[i][2], accS[i][3]};
    *(f32x4*)&Qs[(r0 + i) * STR + c0] = sv;
    denp[(r0 + i) * 16 + tx] = dp[i];
  }
  __syncthreads();  // B5
  if (tid < 64) {
    float s = den[tid];
#pragma unroll
    for (int t = 0; t < 16; t++) s += denp[tid * 16 + t];
    den[tid] = s;
  }

#pragma unroll 2
  for (int c4 = 0; c4 < 64; c4 += 4) {
    f32x4 sf[4], vf[4];
#pragma unroll
    for (int i = 0; i < 4; i++) sf[i] = *(const f32x4*)&Qs[(r0 + i) * STR + c4];
#pragma unroll
    for (int cc = 0; cc < 4; cc++) vf[cc] = *(const f32x4*)&Vs[(c4 + cc) * STR + m0];
#pragma unroll
    for (int i = 0; i < 4; i++)
#pragma unroll
      for (int j = 0; j < 4; j++)
        accO[i][j] += sf[i][0] * vf[0][j] + sf[i][1] * vf[1][j] +
                      sf[i][2] * vf[2][j] + sf[i][3] * vf[3][j];
  }
  __syncthreads();  // B6

#pragma unroll
  for (int i = 0; i < 4; i++) {
    const float inv = 1.f / den[r0 + i];
    short4v ov;
#pragma unroll
    for (int j = 0; j < 4; j++) ov[j] = f2b_bits(accO[i][j] * inv);
    *(short4v*)&O[(size_t)(t0 + r0 + i) * DM + h * 64 + m0] = ov;
  }
}

// ---------------------------------------------------------------------------
// Proj GEMM: 64x64 tiles, BK=64, grid 512 (2 blocks/CU). fp32 out.
// ---------------------------------------------------------------------------
__global__ __launch_bounds__(256) void gemm_proj(const bf16* __restrict__ A,
                                                 const bf16* __restrict__ W,
                                                 const float* __restrict__ bias,
                                                 float* __restrict__ Cout) {
  constexpr int K = 1024;
  __shared__ __align__(16) short As[2 * 64 * 32];
  __shared__ __align__(16) short Bs[2 * 64 * 32];

  const int tid = threadIdx.x;
  const int wid = tid >> 6, lane = tid & 63;
  const int wm = wid >> 1, wn = wid & 1;   // wave tile 32x32
  const int lm = lane & 15, quad = lane >> 4;

  const int m0 = (blockIdx.x & 31) * 64;
  const int n0 = (blockIdx.x >> 5) * 64;
  const short* Ag = (const short*)A;
  const short* Wg = (const short*)W;

  f32x4 zero = {0.f, 0.f, 0.f, 0.f};
  f32x4 acc[2][2];
#pragma unroll
  for (int i = 0; i < 2; i++)
#pragma unroll
    for (int j = 0; j < 2; j++) acc[i][j] = zero;

  for (int kb = 0; kb < K; kb += 64) {
    __syncthreads();
#pragma unroll
    for (int sec = 0; sec < 2; sec++) {
      const int row = tid >> 2, seg = (tid & 3) * 8;
      gload16(&Ag[(size_t)(m0 + row) * K + kb + sec * 32 + seg],
              &As[sec * 2048 + wid * 512]);
      gload16(&Wg[(size_t)(n0 + row) * K + kb + sec * 32 + seg],
              &Bs[sec * 2048 + wid * 512]);
    }
    __syncthreads();
#pragma unroll
    for (int sec = 0; sec < 2; sec++) {
      short8 afr[2], bfr[2];
#pragma unroll
      for (int i = 0; i < 2; i++)
        afr[i] = *(const short8*)&As[sec * 2048 + (wm * 32 + i * 16 + lm) * 32 + quad * 8];
#pragma unroll
      for (int j = 0; j < 2; j++)
        bfr[j] = *(const short8*)&Bs[sec * 2048 + (wn * 32 + j * 16 + lm) * 32 + quad * 8];
#pragma unroll
      for (int i = 0; i < 2; i++)
#pragma unroll
        for (int j = 0; j < 2; j++)
          acc[i][j] = __builtin_amdgcn_mfma_f32_16x16x32_bf16(afr[i], bfr[j], acc[i][j], 0, 0, 0);
    }
  }
#pragma unroll
  for (int i = 0; i < 2; i++) {
    const int rbase = m0 + wm * 32 + i * 16 + quad * 4;
#pragma unroll
    for (int j = 0; j < 2; j++) {
      const int col = n0 + wn * 32 + j * 16 + lm;
      const float bval = bias[col];
#pragma unroll
      for (int r = 0; r < 4; r++)
        Cout[(size_t)(rbase + r) * DM + col] = acc[i][j][r] + bval;
    }
  }
}

// ---------------------------------------------------------------------------
extern "C" void kernel_launch(void* const* d_in, const int* in_sizes, int n_in,
                              void* d_out, int out_size, void* d_ws, size_t ws_size,
                              hipStream_t stream) {
  (void)in_sizes; (void)n_in; (void)out_size; (void)ws_size;
  const float* x      = (const float*)d_in[0];
  const float* ln_g   = (const float*)d_in[1];
  const float* ln_b   = (const float*)d_in[2];
  const float* qkv_w  = (const float*)d_in[3];
  const float* qkv_b  = (const float*)d_in[4];
  const float* gate_w = (const float*)d_in[5];
  const float* gate_b = (const float*)d_in[6];
  const float* proj_w = (const float*)d_in[7];
  const float* proj_b = (const float*)d_in[8];
  float* out = (float*)d_out;

  char* ws = (char*)d_ws;
  size_t off = 0;
  auto alloc = [&](size_t bytes) {
    void* p = ws + off;
    off += (bytes + 255) & ~(size_t)255;
    return p;
  };
  bf16*  xn       = (bf16*)alloc((size_t)T_SEQ * DM * 2);
  bf16*  xbf      = (bf16*)alloc((size_t)T_SEQ * DM * 2);
  bf16*  wqkv     = (bf16*)alloc((size_t)3 * DM * DM * 2);
  bf16*  wgate    = (bf16*)alloc((size_t)DM * DM * 2);
  bf16*  wproj    = (bf16*)alloc((size_t)DM * DM * 2);
  short* Gb       = (short*)alloc((size_t)T_SEQ * DM * 2);
  float* gate_accum = (float*)alloc((size_t)T_SEQ * 4);
  short* Qb       = (short*)alloc((size_t)T_SEQ * DM * 2);
  short* Kb       = (short*)alloc((size_t)T_SEQ * DM * 2);
  short* Vb       = (short*)alloc((size_t)T_SEQ * DM * 2);
  bf16*  Obuf     = (bf16*)alloc((size_t)T_SEQ * DM * 2);
  float* Skv      = (float*)alloc((size_t)NH * NCHUNK * 4096 * 4);
  float* Sk       = (float*)alloc((size_t)NH * NCHUNK * 64 * 4);

  prep_kernel<<<T_SEQ + PREP_WBLOCKS, 256, 0, stream>>>(
      x, ln_g, ln_b, qkv_w, gate_w, proj_w, xn, xbf, wqkv, wgate, wproj, gate_accum);
  gemm_gateqkv<<<dim3(16, 32), 256, 0, stream>>>(xbf, xn, wgate, wqkv, gate_b, qkv_b,
                                                 Gb, gate_accum, Qb, Kb, Vb);
  chunk_sum_mm<<<NH * NCHUNK, 256, 0, stream>>>(Kb, Gb, gate_accum, Vb, Skv, Sk);
  attn_mm<<<NH * NCHUNK, 256, 0, stream>>>(Qb, Kb, Gb, gate_accum, Vb, Skv, Sk, Obuf);
  gemm_proj<<<512, 256, 0, stream>>>(Obuf, wproj, proj_b, out);
}

// Round 10
// 166.263 us; speedup vs baseline: 2.8492x; 1.0241x over previous
//
#include <hip/hip_runtime.h>
#include <hip/hip_bf16.h>
#include <math.h>

#define T_SEQ 2048
#define DM 1024
#define NH 16
#define DH 64
#define CHUNK 64
#define NCHUNK (T_SEQ / CHUNK)   // 32

typedef __hip_bfloat16 bf16;
typedef __attribute__((ext_vector_type(8))) short short8;
typedef __attribute__((ext_vector_type(4))) short short4v;
typedef __attribute__((ext_vector_type(4))) float f32x4;

static __device__ __forceinline__ short f2b_bits(float f) {
  bf16 t = __float2bfloat16(f);
  short s;
  __builtin_memcpy(&s, &t, 2);
  return s;
}
static __device__ __forceinline__ float b2f(short s) {
  unsigned int u = ((unsigned int)(unsigned short)s) << 16;
  float f;
  __builtin_memcpy(&f, &u, 4);
  return f;
}
// gated ELU+1: elu(x)+1 = x>0 ? x+1 : exp(x)
static __device__ __forceinline__ float gelu1(float raw, float gate, float inv) {
  float x = raw * gate * inv;
  return x > 0.f ? x + 1.f : __expf(x);
}
static __device__ __forceinline__ void gload16(const void* g, void* l) {
  __builtin_amdgcn_global_load_lds((const __attribute__((address_space(1))) void*)g,
                                   (__attribute__((address_space(3))) void*)l, 16, 0, 0);
}

// ---------------------------------------------------------------------------
// prep: blocks 0..2047 = LayerNorm rows (blocks 0..7 also zero gate_accum);
//       blocks 2048..  = fp32->bf16 weight conversion (qkv|gate|proj).
// ---------------------------------------------------------------------------
#define PREP_WBLOCKS (5 * DM * DM / 4 / 256)   // 5120
__global__ __launch_bounds__(256) void prep_kernel(
    const float* __restrict__ x, const float* __restrict__ g,
    const float* __restrict__ b, const float* __restrict__ qkv_w,
    const float* __restrict__ gate_w, const float* __restrict__ proj_w,
    bf16* __restrict__ xn, bf16* __restrict__ xbf,
    bf16* __restrict__ wqkv, bf16* __restrict__ wgate, bf16* __restrict__ wproj,
    float* __restrict__ gate_accum) {
  const int blk = blockIdx.x;
  if (blk < T_SEQ) {
    const int row = blk;
    if (row < 8) gate_accum[row * 256 + threadIdx.x] = 0.f;
    const float* xr = x + (size_t)row * DM;
    float vals[4];
    float s = 0.f, s2 = 0.f;
#pragma unroll
    for (int i = 0; i < 4; i++) {
      float v = xr[threadIdx.x + i * 256];
      vals[i] = v;
      s += v;
      s2 += v * v;
    }
#pragma unroll
    for (int m = 1; m < 64; m <<= 1) {
      s += __shfl_xor(s, m, 64);
      s2 += __shfl_xor(s2, m, 64);
    }
    __shared__ float red[8];
    const int wid = threadIdx.x >> 6;
    if ((threadIdx.x & 63) == 0) {
      red[wid] = s;
      red[4 + wid] = s2;
    }
    __syncthreads();
    s = red[0] + red[1] + red[2] + red[3];
    s2 = red[4] + red[5] + red[6] + red[7];
    const float mean = s * (1.f / DM);
    const float var = s2 * (1.f / DM) - mean * mean;
    const float rstd = rsqrtf(var + 1e-5f);
#pragma unroll
    for (int i = 0; i < 4; i++) {
      int idx = threadIdx.x + i * 256;
      float v = (vals[i] - mean) * rstd * g[idx] + b[idx];
      xn[(size_t)row * DM + idx] = __float2bfloat16(v);
      xbf[(size_t)row * DM + idx] = __float2bfloat16(vals[i]);
    }
  } else {
    constexpr int NQ = 3 * DM * DM / 4, NS = DM * DM / 4;
    int i = (blk - T_SEQ) * 256 + threadIdx.x;
    const float* src;
    bf16* dst;
    int j;
    if (i < NQ) { src = qkv_w; dst = wqkv; j = i; }
    else if (i < NQ + NS) { src = gate_w; dst = wgate; j = i - NQ; }
    else { src = proj_w; dst = wproj; j = i - NQ - NS; }
    float4 v = ((const float4*)src)[j];
    short4v sv;
    sv.x = f2b_bits(v.x); sv.y = f2b_bits(v.y); sv.z = f2b_bits(v.z); sv.w = f2b_bits(v.w);
    *(short4v*)&dst[j * 4] = sv;
  }
}

// ---------------------------------------------------------------------------
// Fused gate+qkv GEMM, tile 128x128, BK=64.
// grid (32, 16): x = fused n-tile (0..7 gate, 8..31 qkv) — FAST dim so all 16
// m-blocks of one weight tile land on XCD x%8 (weight fetched into one L2);
// y = m-tile. Gate: sigmoid -> Gb bf16 + row-sum atomics into gate_accum.
// qkv: RAW biased q,k,v scatter [H][T][DH] bf16.
// ---------------------------------------------------------------------------
__global__ __launch_bounds__(256) void gemm_gateqkv(
    const bf16* __restrict__ xbf, const bf16* __restrict__ xn,
    const bf16* __restrict__ wg, const bf16* __restrict__ wq,
    const float* __restrict__ gate_b, const float* __restrict__ qkv_b,
    short* __restrict__ Gb, float* __restrict__ gate_accum,
    short* __restrict__ Qb, short* __restrict__ Kb, short* __restrict__ Vb) {
  constexpr int K = 1024;
  __shared__ __align__(16) short As[2 * 128 * 32];
  __shared__ __align__(16) short Bs[2 * 128 * 32];

  const int tid = threadIdx.x;
  const int wid = tid >> 6, lane = tid & 63;
  const int wm = wid >> 1, wn = wid & 1;
  const int lm = lane & 15, quad = lane >> 4;

  const bool isGate = blockIdx.x < 8;
  const int m0 = blockIdx.y * 128;
  const int n0 = isGate ? blockIdx.x * 128 : (blockIdx.x - 8) * 128;
  const short* Ag = (const short*)(isGate ? xbf : xn);
  const short* Wg = (const short*)(isGate ? wg : wq);

  f32x4 zero = {0.f, 0.f, 0.f, 0.f};
  f32x4 acc[4][4];
#pragma unroll
  for (int i = 0; i < 4; i++)
#pragma unroll
    for (int j = 0; j < 4; j++) acc[i][j] = zero;

  for (int kb = 0; kb < K; kb += 64) {
    __syncthreads();
#pragma unroll
    for (int sec = 0; sec < 2; sec++) {
#pragma unroll
      for (int it = 0; it < 2; it++) {
        const int idx = it * 256 + tid;
        const int row = idx >> 2, seg = (idx & 3) * 8;
        gload16(&Ag[(size_t)(m0 + row) * K + kb + sec * 32 + seg],
                &As[sec * 4096 + (it * 256 + wid * 64) * 8]);
        gload16(&Wg[(size_t)(n0 + row) * K + kb + sec * 32 + seg],
                &Bs[sec * 4096 + (it * 256 + wid * 64) * 8]);
      }
    }
    __syncthreads();
#pragma unroll
    for (int sec = 0; sec < 2; sec++) {
      short8 afr[4], bfr[4];
#pragma unroll
      for (int i = 0; i < 4; i++) {
        afr[i] = *(const short8*)&As[sec * 4096 + (wm * 64 + i * 16 + lm) * 32 + quad * 8];
        bfr[i] = *(const short8*)&Bs[sec * 4096 + (wn * 64 + i * 16 + lm) * 32 + quad * 8];
      }
#pragma unroll
      for (int i = 0; i < 4; i++)
#pragma unroll
        for (int j = 0; j < 4; j++)
          acc[i][j] = __builtin_amdgcn_mfma_f32_16x16x32_bf16(afr[i], bfr[j], acc[i][j], 0, 0, 0);
    }
  }

  // epilogue: C/D layout col = lane&15, row = quad*4 + r
  if (isGate) {
    float* red = (float*)As;   // 128 rows x 32 slots = 16 KB
    __syncthreads();           // MFMA LDS reads done -> safe to reuse As
#pragma unroll
    for (int i = 0; i < 4; i++) {
#pragma unroll
      for (int r = 0; r < 4; r++) {
        const int rowl = wm * 64 + i * 16 + quad * 4 + r;
        const int row = m0 + rowl;
        float rp = 0.f;
#pragma unroll
        for (int j = 0; j < 4; j++) {
          const int col = n0 + wn * 64 + j * 16 + lm;
          float v = acc[i][j][r] + gate_b[col];
          float sig = 1.f / (1.f + __expf(-v));
          Gb[(size_t)row * DM + col] = f2b_bits(sig);
          rp += sig;
        }
        red[rowl * 32 + wn * 16 + lm] = rp;
      }
    }
    __syncthreads();
    if (tid < 128) {
      float s = 0.f;
#pragma unroll
      for (int t2 = 0; t2 < 32; t2++) s += red[tid * 32 + t2];
      atomicAdd(&gate_accum[m0 + tid], s);
    }
  } else {
#pragma unroll
    for (int i = 0; i < 4; i++) {
      const int rbase = m0 + wm * 64 + i * 16 + quad * 4;
#pragma unroll
      for (int j = 0; j < 4; j++) {
        const int col = n0 + wn * 64 + j * 16 + lm;
        const float bval = qkv_b[col];
#pragma unroll
        for (int r = 0; r < 4; r++) {
          const int row = rbase + r;
          const short bv = f2b_bits(acc[i][j][r] + bval);
          if (col < DM) {
            const int d = col;
            Qb[((size_t)(d >> 6) * T_SEQ + row) * DH + (d & 63)] = bv;
          } else if (col < 2 * DM) {
            const int d = col - DM;
            Kb[((size_t)(d >> 6) * T_SEQ + row) * DH + (d & 63)] = bv;
          } else {
            const int d = col - 2 * DM;
            Vb[((size_t)(d >> 6) * T_SEQ + row) * DH + (d & 63)] = bv;
          }
        }
      }
    }
  }
}

// ---------------------------------------------------------------------------
// Pass A: per (h,c) RAW chunk sums Skv_c = Kg^T V, Sk_c = col sums of Kg
// (gating+ELU applied during staging).
// ---------------------------------------------------------------------------
__global__ __launch_bounds__(256, 2) void chunk_sum_mm(const short* __restrict__ Kb,
                                                       const short* __restrict__ Gb,
                                                       const float* __restrict__ ga,
                                                       const short* __restrict__ Vb,
                                                       float* __restrict__ Skv,
                                                       float* __restrict__ Sk) {
  constexpr int STR = 68;
  __shared__ __align__(16) float Ks2[64 * STR];
  __shared__ __align__(16) float Vs2[64 * STR];
  const int b = blockIdx.x;
  const int h = b >> 5, c = b & 31;
  const int tid = threadIdx.x;
  const int ty = tid >> 4, tx = tid & 15;
  const int d0 = ty * 4, m0 = tx * 4;
  const int t0 = c * CHUNK;
  const size_t cb = ((size_t)h * T_SEQ + t0) * DH;
#pragma unroll
  for (int p = 0; p < 4; p++) {
    int f = p * 256 + tid, row = f >> 4, seg = (f & 15) * 4;
    const int t = t0 + row;
    short4v kr = *(const short4v*)&Kb[cb + row * 64 + seg];
    short4v gr = *(const short4v*)&Gb[(size_t)t * DM + h * 64 + seg];
    short4v vr = *(const short4v*)&Vb[cb + row * 64 + seg];
    const float inv = 1.f / (ga[t] * (1.f / DM) + 1e-5f);
    f32x4 kgv, vv;
#pragma unroll
    for (int e = 0; e < 4; e++) {
      kgv[e] = gelu1(b2f(kr[e]), b2f(gr[e]), inv);
      vv[e] = b2f(vr[e]);
    }
    *(f32x4*)&Ks2[row * STR + seg] = kgv;
    *(f32x4*)&Vs2[row * STR + seg] = vv;
  }
  __syncthreads();
  float acc[4][4] = {};
#pragma unroll 4
  for (int s = 0; s < 64; s++) {
    f32x4 kf = *(const f32x4*)&Ks2[s * STR + d0];
    f32x4 vf = *(const f32x4*)&Vs2[s * STR + m0];
#pragma unroll
    for (int i = 0; i < 4; i++)
#pragma unroll
      for (int j = 0; j < 4; j++) acc[i][j] += kf[i] * vf[j];
  }
  float* outp = Skv + (size_t)b * 4096;
#pragma unroll
  for (int i = 0; i < 4; i++) {
    f32x4 o = {acc[i][0], acc[i][1], acc[i][2], acc[i][3]};
    *(f32x4*)&outp[(d0 + i) * 64 + m0] = o;
  }
  if (tid < 64) {
    float ss = 0.f;
#pragma unroll 4
    for (int s = 0; s < 64; s++) ss += Ks2[s * STR + tid];
    Sk[b * 64 + tid] = ss;
  }
}

// ---------------------------------------------------------------------------
// Pass B: exclusive prefix over chunks, one thread per (h,e) chain.
// Grid 260: blocks 0..255 -> Skv chains, 256..259 -> Sk chains.
// ---------------------------------------------------------------------------
__global__ __launch_bounds__(256) void scan_excl(float* __restrict__ Skv,
                                                 float* __restrict__ Sk) {
  const int bid = blockIdx.x, tid = threadIdx.x;
  if (bid < 256) {
    const int id = bid * 256 + tid;
    const int h = id >> 12, e = id & 4095;
    float* base = Skv + (size_t)h * NCHUNK * 4096 + e;
    float v[NCHUNK];
#pragma unroll
    for (int c = 0; c < NCHUNK; c++) v[c] = base[(size_t)c * 4096];
    float run = 0.f;
#pragma unroll
    for (int c = 0; c < NCHUNK; c++) {
      float t = v[c];
      base[(size_t)c * 4096] = run;
      run += t;
    }
  } else {
    const int id = (bid - 256) * 256 + tid;
    const int h = id >> 6, e = id & 63;
    float* base = Sk + (size_t)h * NCHUNK * 64 + e;
    float v[NCHUNK];
#pragma unroll
    for (int c = 0; c < NCHUNK; c++) v[c] = base[c * 64];
    float run = 0.f;
#pragma unroll
    for (int c = 0; c < NCHUNK; c++) {
      float t = v[c];
      base[c * 64] = run;
      run += t;
    }
  }
}

// ---------------------------------------------------------------------------
// Pass C: per (h,c): accO = Q.P ; S = Q K^T (causal) ; accO += S.V ;
// den = q.skp + rowsum(S). Gating+ELU applied to bf16 Q,K during staging.
// All in-loop operands from LDS; P/K share one region.
// ---------------------------------------------------------------------------
__global__ __launch_bounds__(256, 2) void attn_mm(const short* __restrict__ Qb,
                                                  const short* __restrict__ Kb,
                                                  const short* __restrict__ Gb,
                                                  const float* __restrict__ ga,
                                                  const short* __restrict__ Vb,
                                                  const float* __restrict__ Skv,
                                                  const float* __restrict__ Sk,
                                                  bf16* __restrict__ O) {
  constexpr int STR = 68;
  __shared__ __align__(16) float Qs[64 * STR];   // gated Q, later S
  __shared__ __align__(16) float Vs[64 * STR];
  __shared__ __align__(16) float KPs[64 * STR];  // P phase 1, gated K phase 2
  __shared__ float denp[64 * 16];
  __shared__ float skp[64];
  __shared__ float den[64];
  const int b = blockIdx.x;
  const int h = b >> 5, c = b & 31;
  const int tid = threadIdx.x;
  const int ty = tid >> 4, tx = tid & 15;
  const int r0 = ty * 4, c0 = tx * 4, m0 = tx * 4;
  const int t0 = c * CHUNK;
  const size_t cb = ((size_t)h * T_SEQ + t0) * DH;
  const float* Pg = Skv + (size_t)b * 4096;

  // K prefetch (raw + gate + inv) into registers; consumed in phase 2
  short4v kreg[4], greg[4];
  float ireg[4];
#pragma unroll
  for (int q = 0; q < 4; q++) {
    int f = q * 256 + tid, row = f >> 4, seg = (f & 15) * 4;
    kreg[q] = *(const short4v*)&Kb[cb + row * 64 + seg];
    greg[q] = *(const short4v*)&Gb[(size_t)(t0 + row) * DM + h * 64 + seg];
    ireg[q] = 1.f / (ga[t0 + row] * (1.f / DM) + 1e-5f);
  }
  // stage gated Q, V, P (coalesced)
#pragma unroll
  for (int q = 0; q < 4; q++) {
    int f = q * 256 + tid, row = f >> 4, seg = (f & 15) * 4;
    short4v qr = *(const short4v*)&Qb[cb + row * 64 + seg];
    short4v gq = *(const short4v*)&Gb[(size_t)(t0 + row) * DM + h * 64 + seg];
    short4v vr = *(const short4v*)&Vb[cb + row * 64 + seg];
    const float inv = 1.f / (ga[t0 + row] * (1.f / DM) + 1e-5f);
    f32x4 qgv, vv;
#pragma unroll
    for (int e = 0; e < 4; e++) {
      qgv[e] = gelu1(b2f(qr[e]), b2f(gq[e]), inv);
      vv[e] = b2f(vr[e]);
    }
    *(f32x4*)&Qs[row * STR + seg] = qgv;
    *(f32x4*)&Vs[row * STR + seg] = vv;
    *(f32x4*)&KPs[row * STR + seg] = *(const f32x4*)&Pg[row * 64 + seg];
  }
  if (tid < 64) skp[tid] = Sk[b * 64 + tid];
  __syncthreads();  // B1

  if (tid < 64) {
    float s = 1e-5f;
#pragma unroll 4
    for (int d = 0; d < 64; d++) s += Qs[tid * STR + d] * skp[d];
    den[tid] = s;
  }

  float accO[4][4] = {};
#pragma unroll 2
  for (int d0 = 0; d0 < 64; d0 += 4) {
    f32x4 qf[4], pf[4];
#pragma unroll
    for (int i = 0; i < 4; i++) qf[i] = *(const f32x4*)&Qs[(r0 + i) * STR + d0];
#pragma unroll
    for (int dd = 0; dd < 4; dd++) pf[dd] = *(const f32x4*)&KPs[(d0 + dd) * STR + m0];
#pragma unroll
    for (int i = 0; i < 4; i++)
#pragma unroll
      for (int j = 0; j < 4; j++)
        accO[i][j] += qf[i][0] * pf[0][j] + qf[i][1] * pf[1][j] +
                      qf[i][2] * pf[2][j] + qf[i][3] * pf[3][j];
  }
  __syncthreads();  // B2: P reads done -> region becomes gated K
#pragma unroll
  for (int q = 0; q < 4; q++) {
    int f = q * 256 + tid, row = f >> 4, seg = (f & 15) * 4;
    f32x4 kgv;
#pragma unroll
    for (int e = 0; e < 4; e++) kgv[e] = gelu1(b2f(kreg[q][e]), b2f(greg[q][e]), ireg[q]);
    *(f32x4*)&KPs[row * STR + seg] = kgv;
  }
  __syncthreads();  // B3

  float accS[4][4] = {};
#pragma unroll 2
  for (int d0 = 0; d0 < 64; d0 += 4) {
    f32x4 qf[4], kf[4];
#pragma unroll
    for (int i = 0; i < 4; i++) qf[i] = *(const f32x4*)&Qs[(r0 + i) * STR + d0];
#pragma unroll
    for (int j = 0; j < 4; j++) kf[j] = *(const f32x4*)&KPs[(c0 + j) * STR + d0];
#pragma unroll
    for (int i = 0; i < 4; i++)
#pragma unroll
      for (int j = 0; j < 4; j++)
        accS[i][j] += qf[i][0] * kf[j][0] + qf[i][1] * kf[j][1] +
                      qf[i][2] * kf[j][2] + qf[i][3] * kf[j][3];
  }
  float dp[4];
#pragma unroll
  for (int i = 0; i < 4; i++) {
    dp[i] = 0.f;
#pragma unroll
    for (int j = 0; j < 4; j++) {
      float v = (c0 + j) <= (r0 + i) ? accS[i][j] : 0.f;
      accS[i][j] = v;
      dp[i] += v;
    }
  }
  __syncthreads();  // B4: Qs reads complete -> overwrite with S
#pragma unroll
  for (int i = 0; i < 4; i++) {
    f32x4 sv = {accS[i][0], accS[i][1], accS[i][2], accS[i][3]};
    *(f32x4*)&Qs[(r0 + i) * STR + c0] = sv;
    denp[(r0 + i) * 16 + tx] = dp[i];
  }
  __syncthreads();  // B5
  if (tid < 64) {
    float s = den[tid];
#pragma unroll
    for (int t = 0; t < 16; t++) s += denp[tid * 16 + t];
    den[tid] = s;
  }

#pragma unroll 2
  for (int c4 = 0; c4 < 64; c4 += 4) {
    f32x4 sf[4], vf[4];
#pragma unroll
    for (int i = 0; i < 4; i++) sf[i] = *(const f32x4*)&Qs[(r0 + i) * STR + c4];
#pragma unroll
    for (int cc = 0; cc < 4; cc++) vf[cc] = *(const f32x4*)&Vs[(c4 + cc) * STR + m0];
#pragma unroll
    for (int i = 0; i < 4; i++)
#pragma unroll
      for (int j = 0; j < 4; j++)
        accO[i][j] += sf[i][0] * vf[0][j] + sf[i][1] * vf[1][j] +
                      sf[i][2] * vf[2][j] + sf[i][3] * vf[3][j];
  }
  __syncthreads();  // B6

#pragma unroll
  for (int i = 0; i < 4; i++) {
    const float inv = 1.f / den[r0 + i];
    short4v ov;
#pragma unroll
    for (int j = 0; j < 4; j++) ov[j] = f2b_bits(accO[i][j] * inv);
    *(short4v*)&O[(size_t)(t0 + r0 + i) * DM + h * 64 + m0] = ov;
  }
}

// ---------------------------------------------------------------------------
// Proj GEMM: tile 64x128, BK=64, grid (8, 32): x = n-tile (fast dim -> all 32
// m-blocks of one weight tile land on XCD x%8). fp32 out.
// ---------------------------------------------------------------------------
__global__ __launch_bounds__(256) void gemm_proj(const bf16* __restrict__ A,
                                                 const bf16* __restrict__ W,
                                                 const float* __restrict__ bias,
                                                 float* __restrict__ Cout) {
  constexpr int K = 1024;
  __shared__ __align__(16) short As[2 * 64 * 32];
  __shared__ __align__(16) short Bs[2 * 128 * 32];

  const int tid = threadIdx.x;
  const int wid = tid >> 6, lane = tid & 63;
  const int wm = wid >> 1, wn = wid & 1;   // wave tile 32(m) x 64(n)
  const int lm = lane & 15, quad = lane >> 4;

  const int n0 = blockIdx.x * 128;
  const int m0 = blockIdx.y * 64;
  const short* Ag = (const short*)A;
  const short* Wg = (const short*)W;

  f32x4 zero = {0.f, 0.f, 0.f, 0.f};
  f32x4 acc[2][4];
#pragma unroll
  for (int i = 0; i < 2; i++)
#pragma unroll
    for (int j = 0; j < 4; j++) acc[i][j] = zero;

  for (int kb = 0; kb < K; kb += 64) {
    __syncthreads();
#pragma unroll
    for (int sec = 0; sec < 2; sec++) {
      {
        const int row = tid >> 2, seg = (tid & 3) * 8;
        gload16(&Ag[(size_t)(m0 + row) * K + kb + sec * 32 + seg],
                &As[sec * 2048 + (wid * 64) * 8]);
      }
#pragma unroll
      for (int it = 0; it < 2; it++) {
        const int idx = it * 256 + tid;
        const int row = idx >> 2, seg = (idx & 3) * 8;
        gload16(&Wg[(size_t)(n0 + row) * K + kb + sec * 32 + seg],
                &Bs[sec * 4096 + (it * 256 + wid * 64) * 8]);
      }
    }
    __syncthreads();
#pragma unroll
    for (int sec = 0; sec < 2; sec++) {
      short8 afr[2], bfr[4];
#pragma unroll
      for (int i = 0; i < 2; i++)
        afr[i] = *(const short8*)&As[sec * 2048 + (wm * 32 + i * 16 + lm) * 32 + quad * 8];
#pragma unroll
      for (int j = 0; j < 4; j++)
        bfr[j] = *(const short8*)&Bs[sec * 4096 + (wn * 64 + j * 16 + lm) * 32 + quad * 8];
#pragma unroll
      for (int i = 0; i < 2; i++)
#pragma unroll
        for (int j = 0; j < 4; j++)
          acc[i][j] = __builtin_amdgcn_mfma_f32_16x16x32_bf16(afr[i], bfr[j], acc[i][j], 0, 0, 0);
    }
  }
#pragma unroll
  for (int i = 0; i < 2; i++) {
    const int rbase = m0 + wm * 32 + i * 16 + quad * 4;
#pragma unroll
    for (int j = 0; j < 4; j++) {
      const int col = n0 + wn * 64 + j * 16 + lm;
      const float bval = bias[col];
#pragma unroll
      for (int r = 0; r < 4; r++)
        Cout[(size_t)(rbase + r) * DM + col] = acc[i][j][r] + bval;
    }
  }
}

// ---------------------------------------------------------------------------
extern "C" void kernel_launch(void* const* d_in, const int* in_sizes, int n_in,
                              void* d_out, int out_size, void* d_ws, size_t ws_size,
                              hipStream_t stream) {
  (void)in_sizes; (void)n_in; (void)out_size; (void)ws_size;
  const float* x      = (const float*)d_in[0];
  const float* ln_g   = (const float*)d_in[1];
  const float* ln_b   = (const float*)d_in[2];
  const float* qkv_w  = (const float*)d_in[3];
  const float* qkv_b  = (const float*)d_in[4];
  const float* gate_w = (const float*)d_in[5];
  const float* gate_b = (const float*)d_in[6];
  const float* proj_w = (const float*)d_in[7];
  const float* proj_b = (const float*)d_in[8];
  float* out = (float*)d_out;

  char* ws = (char*)d_ws;
  size_t off = 0;
  auto alloc = [&](size_t bytes) {
    void* p = ws + off;
    off += (bytes + 255) & ~(size_t)255;
    return p;
  };
  bf16*  xn       = (bf16*)alloc((size_t)T_SEQ * DM * 2);
  bf16*  xbf      = (bf16*)alloc((size_t)T_SEQ * DM * 2);
  bf16*  wqkv     = (bf16*)alloc((size_t)3 * DM * DM * 2);
  bf16*  wgate    = (bf16*)alloc((size_t)DM * DM * 2);
  bf16*  wproj    = (bf16*)alloc((size_t)DM * DM * 2);
  short* Gb       = (short*)alloc((size_t)T_SEQ * DM * 2);
  float* gate_accum = (float*)alloc((size_t)T_SEQ * 4);
  short* Qb       = (short*)alloc((size_t)T_SEQ * DM * 2);
  short* Kb       = (short*)alloc((size_t)T_SEQ * DM * 2);
  short* Vb       = (short*)alloc((size_t)T_SEQ * DM * 2);
  bf16*  Obuf     = (bf16*)alloc((size_t)T_SEQ * DM * 2);
  float* Skv      = (float*)alloc((size_t)NH * NCHUNK * 4096 * 4);
  float* Sk       = (float*)alloc((size_t)NH * NCHUNK * 64 * 4);

  prep_kernel<<<T_SEQ + PREP_WBLOCKS, 256, 0, stream>>>(
      x, ln_g, ln_b, qkv_w, gate_w, proj_w, xn, xbf, wqkv, wgate, wproj, gate_accum);
  gemm_gateqkv<<<dim3(32, 16), 256, 0, stream>>>(xbf, xn, wgate, wqkv, gate_b, qkv_b,
                                                 Gb, gate_accum, Qb, Kb, Vb);
  chunk_sum_mm<<<NH * NCHUNK, 256, 0, stream>>>(Kb, Gb, gate_accum, Vb, Skv, Sk);
  scan_excl<<<260, 256, 0, stream>>>(Skv, Sk);
  attn_mm<<<NH * NCHUNK, 256, 0, stream>>>(Qb, Kb, Gb, gate_accum, Vb, Skv, Sk, Obuf);
  gemm_proj<<<dim3(8, 32), 256, 0, stream>>>(Obuf, wproj, proj_b, out);
}

// Round 11
// 165.461 us; speedup vs baseline: 2.8630x; 1.0048x over previous
//
#include <hip/hip_runtime.h>
#include <hip/hip_bf16.h>
#include <math.h>

#define T_SEQ 2048
#define DM 1024
#define NH 16
#define DH 64
#define CHUNK 64
#define NCHUNK (T_SEQ / CHUNK)   // 32

typedef __hip_bfloat16 bf16;
typedef __attribute__((ext_vector_type(8))) short short8;
typedef __attribute__((ext_vector_type(4))) short short4v;
typedef __attribute__((ext_vector_type(4))) float f32x4;

static __device__ __forceinline__ short f2b_bits(float f) {
  bf16 t = __float2bfloat16(f);
  short s;
  __builtin_memcpy(&s, &t, 2);
  return s;
}
static __device__ __forceinline__ float b2f(short s) {
  unsigned int u = ((unsigned int)(unsigned short)s) << 16;
  float f;
  __builtin_memcpy(&f, &u, 4);
  return f;
}
// gated ELU+1: elu(x)+1 = x>0 ? x+1 : exp(x)
static __device__ __forceinline__ float gelu1(float raw, float gate, float inv) {
  float x = raw * gate * inv;
  return x > 0.f ? x + 1.f : __expf(x);
}
static __device__ __forceinline__ void gload16(const void* g, void* l) {
  __builtin_amdgcn_global_load_lds((const __attribute__((address_space(1))) void*)g,
                                   (__attribute__((address_space(3))) void*)l, 16, 0, 0);
}

// ---------------------------------------------------------------------------
// prep: blocks 0..2047 = LayerNorm rows (blocks 0..7 also zero gate_accum);
//       blocks 2048..  = fp32->bf16 weight conversion (qkv|gate|proj).
// ---------------------------------------------------------------------------
#define PREP_WBLOCKS (5 * DM * DM / 4 / 256)   // 5120
__global__ __launch_bounds__(256) void prep_kernel(
    const float* __restrict__ x, const float* __restrict__ g,
    const float* __restrict__ b, const float* __restrict__ qkv_w,
    const float* __restrict__ gate_w, const float* __restrict__ proj_w,
    bf16* __restrict__ xn, bf16* __restrict__ xbf,
    bf16* __restrict__ wqkv, bf16* __restrict__ wgate, bf16* __restrict__ wproj,
    float* __restrict__ gate_accum) {
  const int blk = blockIdx.x;
  if (blk < T_SEQ) {
    const int row = blk;
    if (row < 8) gate_accum[row * 256 + threadIdx.x] = 0.f;
    const float* xr = x + (size_t)row * DM;
    float vals[4];
    float s = 0.f, s2 = 0.f;
#pragma unroll
    for (int i = 0; i < 4; i++) {
      float v = xr[threadIdx.x + i * 256];
      vals[i] = v;
      s += v;
      s2 += v * v;
    }
#pragma unroll
    for (int m = 1; m < 64; m <<= 1) {
      s += __shfl_xor(s, m, 64);
      s2 += __shfl_xor(s2, m, 64);
    }
    __shared__ float red[8];
    const int wid = threadIdx.x >> 6;
    if ((threadIdx.x & 63) == 0) {
      red[wid] = s;
      red[4 + wid] = s2;
    }
    __syncthreads();
    s = red[0] + red[1] + red[2] + red[3];
    s2 = red[4] + red[5] + red[6] + red[7];
    const float mean = s * (1.f / DM);
    const float var = s2 * (1.f / DM) - mean * mean;
    const float rstd = rsqrtf(var + 1e-5f);
#pragma unroll
    for (int i = 0; i < 4; i++) {
      int idx = threadIdx.x + i * 256;
      float v = (vals[i] - mean) * rstd * g[idx] + b[idx];
      xn[(size_t)row * DM + idx] = __float2bfloat16(v);
      xbf[(size_t)row * DM + idx] = __float2bfloat16(vals[i]);
    }
  } else {
    constexpr int NQ = 3 * DM * DM / 4, NS = DM * DM / 4;
    int i = (blk - T_SEQ) * 256 + threadIdx.x;
    const float* src;
    bf16* dst;
    int j;
    if (i < NQ) { src = qkv_w; dst = wqkv; j = i; }
    else if (i < NQ + NS) { src = gate_w; dst = wgate; j = i - NQ; }
    else { src = proj_w; dst = wproj; j = i - NQ - NS; }
    float4 v = ((const float4*)src)[j];
    short4v sv;
    sv.x = f2b_bits(v.x); sv.y = f2b_bits(v.y); sv.z = f2b_bits(v.z); sv.w = f2b_bits(v.w);
    *(short4v*)&dst[j * 4] = sv;
  }
}

// ---------------------------------------------------------------------------
// Fused gate+qkv GEMM, tile 128x128, BK=64, grid 512 (1-D) with XCD-region
// swizzle: 8 regions of 8m x 8n tiles; blocks of one XCD (id%8) share both
// operand sets (A: 8 m-tiles, W: 8 n-tiles -> ~4 MB, fits one XCD L2).
// gate: sigmoid -> Gb bf16 + row-sum atomics; qkv: raw q,k scatter + v
// scattered BOTH natural [H][T][DH] and transposed [H][DH][T].
// ---------------------------------------------------------------------------
__global__ __launch_bounds__(256) void gemm_gateqkv(
    const bf16* __restrict__ xbf, const bf16* __restrict__ xn,
    const bf16* __restrict__ wg, const bf16* __restrict__ wq,
    const float* __restrict__ gate_b, const float* __restrict__ qkv_b,
    short* __restrict__ Gb, float* __restrict__ gate_accum,
    short* __restrict__ Qb, short* __restrict__ Kb, short* __restrict__ Vb,
    short* __restrict__ VbT) {
  constexpr int K = 1024;
  __shared__ __align__(16) short As[2 * 128 * 32];
  __shared__ __align__(16) short Bs[2 * 128 * 32];

  const int tid = threadIdx.x;
  const int wid = tid >> 6, lane = tid & 63;
  const int wm = wid >> 1, wn = wid & 1;
  const int lm = lane & 15, quad = lane >> 4;

  // XCD-region swizzle: xcd = id&7 -> region (mg, ng); within-region (jm, jn)
  const int bid = blockIdx.x;
  const int xcd = bid & 7, j = bid >> 3;
  const int mg = xcd & 1, ng = xcd >> 1;
  const int jm = j & 7, jn = j >> 3;
  const int mt = mg * 8 + jm;        // 0..15
  const int nt = ng * 8 + jn;        // 0..31
  const bool isGate = nt < 8;
  const int m0 = mt * 128;
  const int n0 = (isGate ? nt : nt - 8) * 128;
  const short* Ag = (const short*)(isGate ? xbf : xn);
  const short* Wg = (const short*)(isGate ? wg : wq);

  f32x4 zero = {0.f, 0.f, 0.f, 0.f};
  f32x4 acc[4][4];
#pragma unroll
  for (int i = 0; i < 4; i++)
#pragma unroll
    for (int jj = 0; jj < 4; jj++) acc[i][jj] = zero;

  for (int kb = 0; kb < K; kb += 64) {
    __syncthreads();
#pragma unroll
    for (int sec = 0; sec < 2; sec++) {
#pragma unroll
      for (int it = 0; it < 2; it++) {
        const int idx = it * 256 + tid;
        const int row = idx >> 2, seg = (idx & 3) * 8;
        gload16(&Ag[(size_t)(m0 + row) * K + kb + sec * 32 + seg],
                &As[sec * 4096 + (it * 256 + wid * 64) * 8]);
        gload16(&Wg[(size_t)(n0 + row) * K + kb + sec * 32 + seg],
                &Bs[sec * 4096 + (it * 256 + wid * 64) * 8]);
      }
    }
    __syncthreads();
#pragma unroll
    for (int sec = 0; sec < 2; sec++) {
      short8 afr[4], bfr[4];
#pragma unroll
      for (int i = 0; i < 4; i++) {
        afr[i] = *(const short8*)&As[sec * 4096 + (wm * 64 + i * 16 + lm) * 32 + quad * 8];
        bfr[i] = *(const short8*)&Bs[sec * 4096 + (wn * 64 + i * 16 + lm) * 32 + quad * 8];
      }
#pragma unroll
      for (int i = 0; i < 4; i++)
#pragma unroll
        for (int jj = 0; jj < 4; jj++)
          acc[i][jj] = __builtin_amdgcn_mfma_f32_16x16x32_bf16(afr[i], bfr[jj], acc[i][jj], 0, 0, 0);
    }
  }

  // epilogue: C/D layout col = lane&15, row = quad*4 + r
  if (isGate) {
    float* red = (float*)As;   // 128 rows x 32 slots = 16 KB
    __syncthreads();           // MFMA LDS reads done -> safe to reuse As
#pragma unroll
    for (int i = 0; i < 4; i++) {
#pragma unroll
      for (int r = 0; r < 4; r++) {
        const int rowl = wm * 64 + i * 16 + quad * 4 + r;
        const int row = m0 + rowl;
        float rp = 0.f;
#pragma unroll
        for (int jj = 0; jj < 4; jj++) {
          const int col = n0 + wn * 64 + jj * 16 + lm;
          float v = acc[i][jj][r] + gate_b[col];
          float sig = 1.f / (1.f + __expf(-v));
          Gb[(size_t)row * DM + col] = f2b_bits(sig);
          rp += sig;
        }
        red[rowl * 32 + wn * 16 + lm] = rp;
      }
    }
    __syncthreads();
    if (tid < 128) {
      float s = 0.f;
#pragma unroll
      for (int t2 = 0; t2 < 32; t2++) s += red[tid * 32 + t2];
      atomicAdd(&gate_accum[m0 + tid], s);
    }
  } else {
#pragma unroll
    for (int i = 0; i < 4; i++) {
      const int rbase = m0 + wm * 64 + i * 16 + quad * 4;
#pragma unroll
      for (int jj = 0; jj < 4; jj++) {
        const int col = n0 + wn * 64 + jj * 16 + lm;
        const float bval = qkv_b[col];
#pragma unroll
        for (int r = 0; r < 4; r++) {
          const int row = rbase + r;
          const short bv = f2b_bits(acc[i][jj][r] + bval);
          if (col < DM) {
            const int d = col;
            Qb[((size_t)(d >> 6) * T_SEQ + row) * DH + (d & 63)] = bv;
          } else if (col < 2 * DM) {
            const int d = col - DM;
            Kb[((size_t)(d >> 6) * T_SEQ + row) * DH + (d & 63)] = bv;
          } else {
            const int d = col - 2 * DM;
            Vb[((size_t)(d >> 6) * T_SEQ + row) * DH + (d & 63)] = bv;
            VbT[((size_t)(d >> 6) * DH + (d & 63)) * T_SEQ + row] = bv;
          }
        }
      }
    }
  }
}

// ---------------------------------------------------------------------------
// Pass A: per (h,c) RAW chunk sums, stored TRANSPOSED: SkvT[m][d] (for attn's
// O1^T = P^T.Q^T MFMA). Sk_c = col sums of gated K. Gating during staging.
// ---------------------------------------------------------------------------
__global__ __launch_bounds__(256, 2) void chunk_sum_mm(const short* __restrict__ Kb,
                                                       const short* __restrict__ Gb,
                                                       const float* __restrict__ ga,
                                                       const short* __restrict__ Vb,
                                                       float* __restrict__ SkvT,
                                                       float* __restrict__ Sk) {
  constexpr int STR = 68;
  __shared__ __align__(16) float Ks2[64 * STR];
  __shared__ __align__(16) float Vs2[64 * STR];
  const int b = blockIdx.x;
  const int h = b >> 5, c = b & 31;
  const int tid = threadIdx.x;
  const int ty = tid >> 4, tx = tid & 15;
  const int d0 = ty * 4, m0 = tx * 4;
  const int t0 = c * CHUNK;
  const size_t cb = ((size_t)h * T_SEQ + t0) * DH;
#pragma unroll
  for (int p = 0; p < 4; p++) {
    int f = p * 256 + tid, row = f >> 4, seg = (f & 15) * 4;
    const int t = t0 + row;
    short4v kr = *(const short4v*)&Kb[cb + row * 64 + seg];
    short4v gr = *(const short4v*)&Gb[(size_t)t * DM + h * 64 + seg];
    short4v vr = *(const short4v*)&Vb[cb + row * 64 + seg];
    const float inv = 1.f / (ga[t] * (1.f / DM) + 1e-5f);
    f32x4 kgv, vv;
#pragma unroll
    for (int e = 0; e < 4; e++) {
      kgv[e] = gelu1(b2f(kr[e]), b2f(gr[e]), inv);
      vv[e] = b2f(vr[e]);
    }
    *(f32x4*)&Ks2[row * STR + seg] = kgv;
    *(f32x4*)&Vs2[row * STR + seg] = vv;
  }
  __syncthreads();
  float acc[4][4] = {};
#pragma unroll 4
  for (int s = 0; s < 64; s++) {
    f32x4 kf = *(const f32x4*)&Ks2[s * STR + d0];
    f32x4 vf = *(const f32x4*)&Vs2[s * STR + m0];
#pragma unroll
    for (int i = 0; i < 4; i++)
#pragma unroll
      for (int j = 0; j < 4; j++) acc[i][j] += kf[i] * vf[j];
  }
  float* outp = SkvT + (size_t)b * 4096;
  // transposed store: SkvT[m][d] = acc[d][m]
#pragma unroll
  for (int i = 0; i < 4; i++)
#pragma unroll
    for (int j = 0; j < 4; j++)
      outp[(m0 + j) * 64 + (d0 + i)] = acc[i][j];
  if (tid < 64) {
    float ss = 0.f;
#pragma unroll 4
    for (int s = 0; s < 64; s++) ss += Ks2[s * STR + tid];
    Sk[b * 64 + tid] = ss;
  }
}

// ---------------------------------------------------------------------------
// Pass B: exclusive prefix over chunks (elementwise — layout-agnostic, works
// on SkvT). Grid 260.
// ---------------------------------------------------------------------------
__global__ __launch_bounds__(256) void scan_excl(float* __restrict__ Skv,
                                                 float* __restrict__ Sk) {
  const int bid = blockIdx.x, tid = threadIdx.x;
  if (bid < 256) {
    const int id = bid * 256 + tid;
    const int h = id >> 12, e = id & 4095;
    float* base = Skv + (size_t)h * NCHUNK * 4096 + e;
    float v[NCHUNK];
#pragma unroll
    for (int c = 0; c < NCHUNK; c++) v[c] = base[(size_t)c * 4096];
    float run = 0.f;
#pragma unroll
    for (int c = 0; c < NCHUNK; c++) {
      float t = v[c];
      base[(size_t)c * 4096] = run;
      run += t;
    }
  } else {
    const int id = (bid - 256) * 256 + tid;
    const int h = id >> 6, e = id & 63;
    float* base = Sk + (size_t)h * NCHUNK * 64 + e;
    float v[NCHUNK];
#pragma unroll
    for (int c = 0; c < NCHUNK; c++) v[c] = base[c * 64];
    float run = 0.f;
#pragma unroll
    for (int c = 0; c < NCHUNK; c++) {
      float t = v[c];
      base[c * 64] = run;
      run += t;
    }
  }
}

// ---------------------------------------------------------------------------
// Pass C (MFMA): per (h,c), 4 waves.
//   S = Qg.Kg^T          : mfma(a=Qg rows, b=Kg rows)     [wave = t-band]
//   O^T = P^T.Qg^T + V^T.S^T
//       = mfma(a=Pt rows, b=Qg rows) + mfma(a=Vt rows, b=SL rows) [wave = m-band]
//   den[t] = eps + q.skp + rowsum(masked S)  (fp32: shuffle-reduced from S acc)
// All operands row-major bf16 in LDS, K-contiguous (verified gemm_bt pattern).
// ---------------------------------------------------------------------------
__global__ __launch_bounds__(256, 2) void attn_mfma(const short* __restrict__ Qb,
                                                    const short* __restrict__ Kb,
                                                    const short* __restrict__ Gb,
                                                    const float* __restrict__ ga,
                                                    const short* __restrict__ VbT,
                                                    const float* __restrict__ SkvT,
                                                    const float* __restrict__ Sk,
                                                    bf16* __restrict__ O) {
  constexpr int STR = 72;   // shorts/row: 144 B, 16B-aligned frags
  __shared__ __align__(16) short Qs[64 * STR];
  __shared__ __align__(16) short Ks[64 * STR];
  __shared__ __align__(16) short Vt[64 * STR];   // V^T rows [m][t]
  __shared__ __align__(16) short Pt[64 * STR];   // P^T rows [m][d]
  __shared__ __align__(16) short SL[64 * STR];   // S rows [t][s] bf16
  __shared__ float denp[64], invden[64], skp[64];
  const int b = blockIdx.x;
  const int h = b >> 5, c = b & 31;
  const int tid = threadIdx.x;
  const int wid = tid >> 6, lane = tid & 63;
  const int lm = lane & 15, quad = lane >> 4;
  const int t0 = c * CHUNK;
  const size_t cb = ((size_t)h * T_SEQ + t0) * DH;
  const float* Pg = SkvT + (size_t)b * 4096;

  // stage: gated Q, gated K (natural rows), V^T rows, P^T rows (fp32->bf16)
#pragma unroll
  for (int p = 0; p < 4; p++) {
    const int f = p * 256 + tid, row = f >> 4, seg = (f & 15) * 4;
    const int t = t0 + row;
    short4v qr = *(const short4v*)&Qb[cb + row * 64 + seg];
    short4v kr = *(const short4v*)&Kb[cb + row * 64 + seg];
    short4v gr = *(const short4v*)&Gb[(size_t)t * DM + h * 64 + seg];
    short4v vtr = *(const short4v*)&VbT[((size_t)h * DH + row) * T_SEQ + t0 + seg];
    f32x4 pr = *(const f32x4*)&Pg[row * 64 + seg];
    const float inv = 1.f / (ga[t] * (1.f / DM) + 1e-5f);
    short4v qs, ks, ps;
#pragma unroll
    for (int e = 0; e < 4; e++) {
      qs[e] = f2b_bits(gelu1(b2f(qr[e]), b2f(gr[e]), inv));
      ks[e] = f2b_bits(gelu1(b2f(kr[e]), b2f(gr[e]), inv));
      ps[e] = f2b_bits(pr[e]);
    }
    *(short4v*)&Qs[row * STR + seg] = qs;
    *(short4v*)&Ks[row * STR + seg] = ks;
    *(short4v*)&Vt[row * STR + seg] = vtr;
    *(short4v*)&Pt[row * STR + seg] = ps;
  }
  if (tid < 64) skp[tid] = Sk[b * 64 + tid];
  __syncthreads();  // B1

  f32x4 zero = {0.f, 0.f, 0.f, 0.f};
  // ---- S = Qg.Kg^T (wave wid = t-band wid*16) ----
  short8 aq[2];
#pragma unroll
  for (int ks = 0; ks < 2; ks++)
    aq[ks] = *(const short8*)&Qs[(wid * 16 + lm) * STR + ks * 32 + quad * 8];
  f32x4 accs[4];
#pragma unroll
  for (int j = 0; j < 4; j++) accs[j] = zero;
#pragma unroll
  for (int j = 0; j < 4; j++)
#pragma unroll
    for (int ks = 0; ks < 2; ks++) {
      short8 bk = *(const short8*)&Ks[(j * 16 + lm) * STR + ks * 32 + quad * 8];
      accs[j] = __builtin_amdgcn_mfma_f32_16x16x32_bf16(aq[ks], bk, accs[j], 0, 0, 0);
    }
  // causal mask (C/D: col s = j*16+lm, row t = wid*16+quad*4+r) + fp32 rowsum
  float rowpart[4] = {0.f, 0.f, 0.f, 0.f};
#pragma unroll
  for (int j = 0; j < 4; j++) {
    const int s = j * 16 + lm;
#pragma unroll
    for (int r = 0; r < 4; r++) {
      const int t = wid * 16 + quad * 4 + r;
      float v = (s <= t) ? accs[j][r] : 0.f;
      accs[j][r] = v;
      rowpart[r] += v;
    }
  }
#pragma unroll
  for (int msk = 1; msk < 16; msk <<= 1)
#pragma unroll
    for (int r = 0; r < 4; r++) rowpart[r] += __shfl_xor(rowpart[r], msk, 64);
  if (lm == 0)
#pragma unroll
    for (int r = 0; r < 4; r++) denp[wid * 16 + quad * 4 + r] = rowpart[r];
  // write S to LDS bf16 (rows [t][s])
#pragma unroll
  for (int j = 0; j < 4; j++)
#pragma unroll
    for (int r = 0; r < 4; r++)
      SL[(wid * 16 + quad * 4 + r) * STR + j * 16 + lm] = f2b_bits(accs[j][r]);

  // ---- O1^T = P^T.Qg^T (wave wid = m-band wid*16; cols = t) ----
  f32x4 acco[4];
#pragma unroll
  for (int j = 0; j < 4; j++) acco[j] = zero;
  short8 ap[2];
#pragma unroll
  for (int ks = 0; ks < 2; ks++)
    ap[ks] = *(const short8*)&Pt[(wid * 16 + lm) * STR + ks * 32 + quad * 8];
#pragma unroll
  for (int j = 0; j < 4; j++)
#pragma unroll
    for (int ks = 0; ks < 2; ks++) {
      short8 bq = *(const short8*)&Qs[(j * 16 + lm) * STR + ks * 32 + quad * 8];
      acco[j] = __builtin_amdgcn_mfma_f32_16x16x32_bf16(ap[ks], bq, acco[j], 0, 0, 0);
    }
  __syncthreads();  // B2: SL + denp complete

  // den finalize (fp32): den[t] = eps + q.skp + rowsum
  if (tid < 64) {
    float s = 1e-5f + denp[tid];
    for (int d = 0; d < 64; d++) s += b2f(Qs[tid * STR + d]) * skp[d];
    invden[tid] = 1.f / s;
  }

  // ---- O2^T += V^T.S^T ----
  short8 av[2];
#pragma unroll
  for (int ks = 0; ks < 2; ks++)
    av[ks] = *(const short8*)&Vt[(wid * 16 + lm) * STR + ks * 32 + quad * 8];
#pragma unroll
  for (int j = 0; j < 4; j++)
#pragma unroll
    for (int ks = 0; ks < 2; ks++) {
      short8 bs = *(const short8*)&SL[(j * 16 + lm) * STR + ks * 32 + quad * 8];
      acco[j] = __builtin_amdgcn_mfma_f32_16x16x32_bf16(av[ks], bs, acco[j], 0, 0, 0);
    }
  __syncthreads();  // B3: invden ready

  // store: O^T C/D col = t (j*16+lm), row = m (wid*16+quad*4+r); 4 r's are
  // contiguous in m -> short4 store to O[t][h*64+m]
#pragma unroll
  for (int j = 0; j < 4; j++) {
    const int t = j * 16 + lm;
    const float idv = invden[t];
    short4v ov;
#pragma unroll
    for (int r = 0; r < 4; r++) ov[r] = f2b_bits(acco[j][r] * idv);
    *(short4v*)&((short*)O)[(size_t)(t0 + t) * DM + h * 64 + wid * 16 + quad * 4] = ov;
  }
}

// ---------------------------------------------------------------------------
// Proj GEMM: tile 64x128, BK=64, grid (8, 32). fp32 out.
// ---------------------------------------------------------------------------
__global__ __launch_bounds__(256) void gemm_proj(const bf16* __restrict__ A,
                                                 const bf16* __restrict__ W,
                                                 const float* __restrict__ bias,
                                                 float* __restrict__ Cout) {
  constexpr int K = 1024;
  __shared__ __align__(16) short As[2 * 64 * 32];
  __shared__ __align__(16) short Bs[2 * 128 * 32];

  const int tid = threadIdx.x;
  const int wid = tid >> 6, lane = tid & 63;
  const int wm = wid >> 1, wn = wid & 1;   // wave tile 32(m) x 64(n)
  const int lm = lane & 15, quad = lane >> 4;

  const int n0 = blockIdx.x * 128;
  const int m0 = blockIdx.y * 64;
  const short* Ag = (const short*)A;
  const short* Wg = (const short*)W;

  f32x4 zero = {0.f, 0.f, 0.f, 0.f};
  f32x4 acc[2][4];
#pragma unroll
  for (int i = 0; i < 2; i++)
#pragma unroll
    for (int j = 0; j < 4; j++) acc[i][j] = zero;

  for (int kb = 0; kb < K; kb += 64) {
    __syncthreads();
#pragma unroll
    for (int sec = 0; sec < 2; sec++) {
      {
        const int row = tid >> 2, seg = (tid & 3) * 8;
        gload16(&Ag[(size_t)(m0 + row) * K + kb + sec * 32 + seg],
                &As[sec * 2048 + (wid * 64) * 8]);
      }
#pragma unroll
      for (int it = 0; it < 2; it++) {
        const int idx = it * 256 + tid;
        const int row = idx >> 2, seg = (idx & 3) * 8;
        gload16(&Wg[(size_t)(n0 + row) * K + kb + sec * 32 + seg],
                &Bs[sec * 4096 + (it * 256 + wid * 64) * 8]);
      }
    }
    __syncthreads();
#pragma unroll
    for (int sec = 0; sec < 2; sec++) {
      short8 afr[2], bfr[4];
#pragma unroll
      for (int i = 0; i < 2; i++)
        afr[i] = *(const short8*)&As[sec * 2048 + (wm * 32 + i * 16 + lm) * 32 + quad * 8];
#pragma unroll
      for (int j = 0; j < 4; j++)
        bfr[j] = *(const short8*)&Bs[sec * 4096 + (wn * 64 + j * 16 + lm) * 32 + quad * 8];
#pragma unroll
      for (int i = 0; i < 2; i++)
#pragma unroll
        for (int j = 0; j < 4; j++)
          acc[i][j] = __builtin_amdgcn_mfma_f32_16x16x32_bf16(afr[i], bfr[j], acc[i][j], 0, 0, 0);
    }
  }
#pragma unroll
  for (int i = 0; i < 2; i++) {
    const int rbase = m0 + wm * 32 + i * 16 + quad * 4;
#pragma unroll
    for (int j = 0; j < 4; j++) {
      const int col = n0 + wn * 64 + j * 16 + lm;
      const float bval = bias[col];
#pragma unroll
      for (int r = 0; r < 4; r++)
        Cout[(size_t)(rbase + r) * DM + col] = acc[i][j][r] + bval;
    }
  }
}

// ---------------------------------------------------------------------------
extern "C" void kernel_launch(void* const* d_in, const int* in_sizes, int n_in,
                              void* d_out, int out_size, void* d_ws, size_t ws_size,
                              hipStream_t stream) {
  (void)in_sizes; (void)n_in; (void)out_size; (void)ws_size;
  const float* x      = (const float*)d_in[0];
  const float* ln_g   = (const float*)d_in[1];
  const float* ln_b   = (const float*)d_in[2];
  const float* qkv_w  = (const float*)d_in[3];
  const float* qkv_b  = (const float*)d_in[4];
  const float* gate_w = (const float*)d_in[5];
  const float* gate_b = (const float*)d_in[6];
  const float* proj_w = (const float*)d_in[7];
  const float* proj_b = (const float*)d_in[8];
  float* out = (float*)d_out;

  char* ws = (char*)d_ws;
  size_t off = 0;
  auto alloc = [&](size_t bytes) {
    void* p = ws + off;
    off += (bytes + 255) & ~(size_t)255;
    return p;
  };
  bf16*  xn       = (bf16*)alloc((size_t)T_SEQ * DM * 2);
  bf16*  xbf      = (bf16*)alloc((size_t)T_SEQ * DM * 2);
  bf16*  wqkv     = (bf16*)alloc((size_t)3 * DM * DM * 2);
  bf16*  wgate    = (bf16*)alloc((size_t)DM * DM * 2);
  bf16*  wproj    = (bf16*)alloc((size_t)DM * DM * 2);
  short* Gb       = (short*)alloc((size_t)T_SEQ * DM * 2);
  float* gate_accum = (float*)alloc((size_t)T_SEQ * 4);
  short* Qb       = (short*)alloc((size_t)T_SEQ * DM * 2);
  short* Kb       = (short*)alloc((size_t)T_SEQ * DM * 2);
  short* Vb       = (short*)alloc((size_t)T_SEQ * DM * 2);
  short* VbT      = (short*)alloc((size_t)T_SEQ * DM * 2);
  bf16*  Obuf     = (bf16*)alloc((size_t)T_SEQ * DM * 2);
  float* SkvT     = (float*)alloc((size_t)NH * NCHUNK * 4096 * 4);
  float* Sk       = (float*)alloc((size_t)NH * NCHUNK * 64 * 4);

  prep_kernel<<<T_SEQ + PREP_WBLOCKS, 256, 0, stream>>>(
      x, ln_g, ln_b, qkv_w, gate_w, proj_w, xn, xbf, wqkv, wgate, wproj, gate_accum);
  gemm_gateqkv<<<512, 256, 0, stream>>>(xbf, xn, wgate, wqkv, gate_b, qkv_b,
                                        Gb, gate_accum, Qb, Kb, Vb, VbT);
  chunk_sum_mm<<<NH * NCHUNK, 256, 0, stream>>>(Kb, Gb, gate_accum, Vb, SkvT, Sk);
  scan_excl<<<260, 256, 0, stream>>>(SkvT, Sk);
  attn_mfma<<<NH * NCHUNK, 256, 0, stream>>>(Qb, Kb, Gb, gate_accum, VbT, SkvT, Sk, Obuf);
  gemm_proj<<<dim3(8, 32), 256, 0, stream>>>(Obuf, wproj, proj_b, out);
}

// Round 12
// 162.176 us; speedup vs baseline: 2.9210x; 1.0203x over previous
//
#include <hip/hip_runtime.h>
#include <hip/hip_bf16.h>
#include <math.h>

#define T_SEQ 2048
#define DM 1024
#define NH 16
#define DH 64
#define CHUNK 64
#define NCHUNK (T_SEQ / CHUNK)   // 32

typedef __hip_bfloat16 bf16;
typedef __attribute__((ext_vector_type(8))) short short8;
typedef __attribute__((ext_vector_type(4))) short short4v;
typedef __attribute__((ext_vector_type(4))) float f32x4;

static __device__ __forceinline__ short f2b_bits(float f) {
  bf16 t = __float2bfloat16(f);
  short s;
  __builtin_memcpy(&s, &t, 2);
  return s;
}
static __device__ __forceinline__ float b2f(short s) {
  unsigned int u = ((unsigned int)(unsigned short)s) << 16;
  float f;
  __builtin_memcpy(&f, &u, 4);
  return f;
}
// gated ELU+1: elu(x)+1 = x>0 ? x+1 : exp(x)
static __device__ __forceinline__ float gelu1(float raw, float gate, float inv) {
  float x = raw * gate * inv;
  return x > 0.f ? x + 1.f : __expf(x);
}
static __device__ __forceinline__ void gload16(const void* g, void* l) {
  __builtin_amdgcn_global_load_lds((const __attribute__((address_space(1))) void*)g,
                                   (__attribute__((address_space(3))) void*)l, 16, 0, 0);
}

// ---------------------------------------------------------------------------
// prep: blocks 0..2047 = LayerNorm rows (blocks 0..7 also zero gate_accum);
//       blocks 2048..  = fp32->bf16 weight conversion (qkv|gate|proj).
// ---------------------------------------------------------------------------
#define PREP_WBLOCKS (5 * DM * DM / 4 / 256)   // 5120
__global__ __launch_bounds__(256) void prep_kernel(
    const float* __restrict__ x, const float* __restrict__ g,
    const float* __restrict__ b, const float* __restrict__ qkv_w,
    const float* __restrict__ gate_w, const float* __restrict__ proj_w,
    bf16* __restrict__ xn, bf16* __restrict__ xbf,
    bf16* __restrict__ wqkv, bf16* __restrict__ wgate, bf16* __restrict__ wproj,
    float* __restrict__ gate_accum) {
  const int blk = blockIdx.x;
  if (blk < T_SEQ) {
    const int row = blk;
    if (row < 8) gate_accum[row * 256 + threadIdx.x] = 0.f;
    const float* xr = x + (size_t)row * DM;
    float vals[4];
    float s = 0.f, s2 = 0.f;
#pragma unroll
    for (int i = 0; i < 4; i++) {
      float v = xr[threadIdx.x + i * 256];
      vals[i] = v;
      s += v;
      s2 += v * v;
    }
#pragma unroll
    for (int m = 1; m < 64; m <<= 1) {
      s += __shfl_xor(s, m, 64);
      s2 += __shfl_xor(s2, m, 64);
    }
    __shared__ float red[8];
    const int wid = threadIdx.x >> 6;
    if ((threadIdx.x & 63) == 0) {
      red[wid] = s;
      red[4 + wid] = s2;
    }
    __syncthreads();
    s = red[0] + red[1] + red[2] + red[3];
    s2 = red[4] + red[5] + red[6] + red[7];
    const float mean = s * (1.f / DM);
    const float var = s2 * (1.f / DM) - mean * mean;
    const float rstd = rsqrtf(var + 1e-5f);
#pragma unroll
    for (int i = 0; i < 4; i++) {
      int idx = threadIdx.x + i * 256;
      float v = (vals[i] - mean) * rstd * g[idx] + b[idx];
      xn[(size_t)row * DM + idx] = __float2bfloat16(v);
      xbf[(size_t)row * DM + idx] = __float2bfloat16(vals[i]);
    }
  } else {
    constexpr int NQ = 3 * DM * DM / 4, NS = DM * DM / 4;
    int i = (blk - T_SEQ) * 256 + threadIdx.x;
    const float* src;
    bf16* dst;
    int j;
    if (i < NQ) { src = qkv_w; dst = wqkv; j = i; }
    else if (i < NQ + NS) { src = gate_w; dst = wgate; j = i - NQ; }
    else { src = proj_w; dst = wproj; j = i - NQ - NS; }
    float4 v = ((const float4*)src)[j];
    short4v sv;
    sv.x = f2b_bits(v.x); sv.y = f2b_bits(v.y); sv.z = f2b_bits(v.z); sv.w = f2b_bits(v.w);
    *(short4v*)&dst[j * 4] = sv;
  }
}

// ---------------------------------------------------------------------------
// Fused gate+qkv GEMM, tile 64x128, BK=64, grid (32, 32) = 1024 blocks
// (4 blocks/CU — R11's 512-block/128-tile ran at 13% occupancy, latency-
// bound). x = fused n-tile (0..7 gate, 8..31 qkv), FAST dim: same-n blocks
// have id-stride 32 -> one XCD per weight tile. y = m-tile (64 rows).
// ---------------------------------------------------------------------------
__global__ __launch_bounds__(256) void gemm_gateqkv(
    const bf16* __restrict__ xbf, const bf16* __restrict__ xn,
    const bf16* __restrict__ wg, const bf16* __restrict__ wq,
    const float* __restrict__ gate_b, const float* __restrict__ qkv_b,
    short* __restrict__ Gb, float* __restrict__ gate_accum,
    short* __restrict__ Qb, short* __restrict__ Kb, short* __restrict__ Vb,
    short* __restrict__ VbT) {
  constexpr int K = 1024;
  __shared__ __align__(16) short As[2 * 64 * 32];    // 8 KB
  __shared__ __align__(16) short Bs[2 * 128 * 32];   // 16 KB

  const int tid = threadIdx.x;
  const int wid = tid >> 6, lane = tid & 63;
  const int wm = wid >> 1, wn = wid & 1;   // wave tile 32(m) x 64(n)
  const int lm = lane & 15, quad = lane >> 4;

  const int nt = blockIdx.x;
  const bool isGate = nt < 8;
  const int m0 = blockIdx.y * 64;
  const int n0 = (isGate ? nt : nt - 8) * 128;
  const short* Ag = (const short*)(isGate ? xbf : xn);
  const short* Wg = (const short*)(isGate ? wg : wq);

  f32x4 zero = {0.f, 0.f, 0.f, 0.f};
  f32x4 acc[2][4];
#pragma unroll
  for (int i = 0; i < 2; i++)
#pragma unroll
    for (int j = 0; j < 4; j++) acc[i][j] = zero;

  for (int kb = 0; kb < K; kb += 64) {
    __syncthreads();
#pragma unroll
    for (int sec = 0; sec < 2; sec++) {
      {  // A: 64 rows x 32 shorts = one 256-lane issue
        const int row = tid >> 2, seg = (tid & 3) * 8;
        gload16(&Ag[(size_t)(m0 + row) * K + kb + sec * 32 + seg],
                &As[sec * 2048 + wid * 512]);
      }
#pragma unroll
      for (int it = 0; it < 2; it++) {
        const int idx = it * 256 + tid;
        const int row = idx >> 2, seg = (idx & 3) * 8;
        gload16(&Wg[(size_t)(n0 + row) * K + kb + sec * 32 + seg],
                &Bs[sec * 4096 + (it * 256 + wid * 64) * 8]);
      }
    }
    __syncthreads();
#pragma unroll
    for (int sec = 0; sec < 2; sec++) {
      short8 afr[2], bfr[4];
#pragma unroll
      for (int i = 0; i < 2; i++)
        afr[i] = *(const short8*)&As[sec * 2048 + (wm * 32 + i * 16 + lm) * 32 + quad * 8];
#pragma unroll
      for (int j = 0; j < 4; j++)
        bfr[j] = *(const short8*)&Bs[sec * 4096 + (wn * 64 + j * 16 + lm) * 32 + quad * 8];
#pragma unroll
      for (int i = 0; i < 2; i++)
#pragma unroll
        for (int j = 0; j < 4; j++)
          acc[i][j] = __builtin_amdgcn_mfma_f32_16x16x32_bf16(afr[i], bfr[j], acc[i][j], 0, 0, 0);
    }
  }

  // epilogue: C/D layout col = lane&15, row = quad*4 + r
  if (isGate) {
    float* red = (float*)As;   // 64 rows x 32 slots = 8 KB (fits As exactly)
    __syncthreads();           // MFMA LDS reads done -> safe to reuse As
#pragma unroll
    for (int i = 0; i < 2; i++) {
#pragma unroll
      for (int r = 0; r < 4; r++) {
        const int rowl = wm * 32 + i * 16 + quad * 4 + r;
        const int row = m0 + rowl;
        float rp = 0.f;
#pragma unroll
        for (int j = 0; j < 4; j++) {
          const int col = n0 + wn * 64 + j * 16 + lm;
          float v = acc[i][j][r] + gate_b[col];
          float sig = 1.f / (1.f + __expf(-v));
          Gb[(size_t)row * DM + col] = f2b_bits(sig);
          rp += sig;
        }
        red[rowl * 32 + wn * 16 + lm] = rp;
      }
    }
    __syncthreads();
    if (tid < 64) {
      float s = 0.f;
#pragma unroll
      for (int t2 = 0; t2 < 32; t2++) s += red[tid * 32 + t2];
      atomicAdd(&gate_accum[m0 + tid], s);
    }
  } else {
#pragma unroll
    for (int i = 0; i < 2; i++) {
      const int rbase = m0 + wm * 32 + i * 16 + quad * 4;
#pragma unroll
      for (int j = 0; j < 4; j++) {
        const int col = n0 + wn * 64 + j * 16 + lm;
        const float bval = qkv_b[col];
#pragma unroll
        for (int r = 0; r < 4; r++) {
          const int row = rbase + r;
          const short bv = f2b_bits(acc[i][j][r] + bval);
          if (col < DM) {
            const int d = col;
            Qb[((size_t)(d >> 6) * T_SEQ + row) * DH + (d & 63)] = bv;
          } else if (col < 2 * DM) {
            const int d = col - DM;
            Kb[((size_t)(d >> 6) * T_SEQ + row) * DH + (d & 63)] = bv;
          } else {
            const int d = col - 2 * DM;
            Vb[((size_t)(d >> 6) * T_SEQ + row) * DH + (d & 63)] = bv;
            VbT[((size_t)(d >> 6) * DH + (d & 63)) * T_SEQ + row] = bv;
          }
        }
      }
    }
  }
}

// ---------------------------------------------------------------------------
// Pass A: per (h,c) RAW chunk sums, stored TRANSPOSED: SkvT[m][d]. Sk_c = col
// sums of gated K. Gating during staging.
// ---------------------------------------------------------------------------
__global__ __launch_bounds__(256, 2) void chunk_sum_mm(const short* __restrict__ Kb,
                                                       const short* __restrict__ Gb,
                                                       const float* __restrict__ ga,
                                                       const short* __restrict__ Vb,
                                                       float* __restrict__ SkvT,
                                                       float* __restrict__ Sk) {
  constexpr int STR = 68;
  __shared__ __align__(16) float Ks2[64 * STR];
  __shared__ __align__(16) float Vs2[64 * STR];
  const int b = blockIdx.x;
  const int h = b >> 5, c = b & 31;
  const int tid = threadIdx.x;
  const int ty = tid >> 4, tx = tid & 15;
  const int d0 = ty * 4, m0 = tx * 4;
  const int t0 = c * CHUNK;
  const size_t cb = ((size_t)h * T_SEQ + t0) * DH;
#pragma unroll
  for (int p = 0; p < 4; p++) {
    int f = p * 256 + tid, row = f >> 4, seg = (f & 15) * 4;
    const int t = t0 + row;
    short4v kr = *(const short4v*)&Kb[cb + row * 64 + seg];
    short4v gr = *(const short4v*)&Gb[(size_t)t * DM + h * 64 + seg];
    short4v vr = *(const short4v*)&Vb[cb + row * 64 + seg];
    const float inv = 1.f / (ga[t] * (1.f / DM) + 1e-5f);
    f32x4 kgv, vv;
#pragma unroll
    for (int e = 0; e < 4; e++) {
      kgv[e] = gelu1(b2f(kr[e]), b2f(gr[e]), inv);
      vv[e] = b2f(vr[e]);
    }
    *(f32x4*)&Ks2[row * STR + seg] = kgv;
    *(f32x4*)&Vs2[row * STR + seg] = vv;
  }
  __syncthreads();
  float acc[4][4] = {};
#pragma unroll 4
  for (int s = 0; s < 64; s++) {
    f32x4 kf = *(const f32x4*)&Ks2[s * STR + d0];
    f32x4 vf = *(const f32x4*)&Vs2[s * STR + m0];
#pragma unroll
    for (int i = 0; i < 4; i++)
#pragma unroll
      for (int j = 0; j < 4; j++) acc[i][j] += kf[i] * vf[j];
  }
  float* outp = SkvT + (size_t)b * 4096;
  // transposed store: SkvT[m][d] = acc[d][m]
#pragma unroll
  for (int i = 0; i < 4; i++)
#pragma unroll
    for (int j = 0; j < 4; j++)
      outp[(m0 + j) * 64 + (d0 + i)] = acc[i][j];
  if (tid < 64) {
    float ss = 0.f;
#pragma unroll 4
    for (int s = 0; s < 64; s++) ss += Ks2[s * STR + tid];
    Sk[b * 64 + tid] = ss;
  }
}

// ---------------------------------------------------------------------------
// Pass B: exclusive prefix over chunks (elementwise, layout-agnostic).
// ---------------------------------------------------------------------------
__global__ __launch_bounds__(256) void scan_excl(float* __restrict__ Skv,
                                                 float* __restrict__ Sk) {
  const int bid = blockIdx.x, tid = threadIdx.x;
  if (bid < 256) {
    const int id = bid * 256 + tid;
    const int h = id >> 12, e = id & 4095;
    float* base = Skv + (size_t)h * NCHUNK * 4096 + e;
    float v[NCHUNK];
#pragma unroll
    for (int c = 0; c < NCHUNK; c++) v[c] = base[(size_t)c * 4096];
    float run = 0.f;
#pragma unroll
    for (int c = 0; c < NCHUNK; c++) {
      float t = v[c];
      base[(size_t)c * 4096] = run;
      run += t;
    }
  } else {
    const int id = (bid - 256) * 256 + tid;
    const int h = id >> 6, e = id & 63;
    float* base = Sk + (size_t)h * NCHUNK * 64 + e;
    float v[NCHUNK];
#pragma unroll
    for (int c = 0; c < NCHUNK; c++) v[c] = base[c * 64];
    float run = 0.f;
#pragma unroll
    for (int c = 0; c < NCHUNK; c++) {
      float t = v[c];
      base[c * 64] = run;
      run += t;
    }
  }
}

// ---------------------------------------------------------------------------
// Pass C (MFMA): per (h,c), 4 waves.
//   S = Qg.Kg^T; O^T = P^T.Qg^T + V^T.S^T; den from masked-S rowsum + q.skp.
// ---------------------------------------------------------------------------
__global__ __launch_bounds__(256, 2) void attn_mfma(const short* __restrict__ Qb,
                                                    const short* __restrict__ Kb,
                                                    const short* __restrict__ Gb,
                                                    const float* __restrict__ ga,
                                                    const short* __restrict__ VbT,
                                                    const float* __restrict__ SkvT,
                                                    const float* __restrict__ Sk,
                                                    bf16* __restrict__ O) {
  constexpr int STR = 72;
  __shared__ __align__(16) short Qs[64 * STR];
  __shared__ __align__(16) short Ks[64 * STR];
  __shared__ __align__(16) short Vt[64 * STR];
  __shared__ __align__(16) short Pt[64 * STR];
  __shared__ __align__(16) short SL[64 * STR];
  __shared__ float denp[64], invden[64], skp[64];
  const int b = blockIdx.x;
  const int h = b >> 5, c = b & 31;
  const int tid = threadIdx.x;
  const int wid = tid >> 6, lane = tid & 63;
  const int lm = lane & 15, quad = lane >> 4;
  const int t0 = c * CHUNK;
  const size_t cb = ((size_t)h * T_SEQ + t0) * DH;
  const float* Pg = SkvT + (size_t)b * 4096;

#pragma unroll
  for (int p = 0; p < 4; p++) {
    const int f = p * 256 + tid, row = f >> 4, seg = (f & 15) * 4;
    const int t = t0 + row;
    short4v qr = *(const short4v*)&Qb[cb + row * 64 + seg];
    short4v kr = *(const short4v*)&Kb[cb + row * 64 + seg];
    short4v gr = *(const short4v*)&Gb[(size_t)t * DM + h * 64 + seg];
    short4v vtr = *(const short4v*)&VbT[((size_t)h * DH + row) * T_SEQ + t0 + seg];
    f32x4 pr = *(const f32x4*)&Pg[row * 64 + seg];
    const float inv = 1.f / (ga[t] * (1.f / DM) + 1e-5f);
    short4v qs, ks, ps;
#pragma unroll
    for (int e = 0; e < 4; e++) {
      qs[e] = f2b_bits(gelu1(b2f(qr[e]), b2f(gr[e]), inv));
      ks[e] = f2b_bits(gelu1(b2f(kr[e]), b2f(gr[e]), inv));
      ps[e] = f2b_bits(pr[e]);
    }
    *(short4v*)&Qs[row * STR + seg] = qs;
    *(short4v*)&Ks[row * STR + seg] = ks;
    *(short4v*)&Vt[row * STR + seg] = vtr;
    *(short4v*)&Pt[row * STR + seg] = ps;
  }
  if (tid < 64) skp[tid] = Sk[b * 64 + tid];
  __syncthreads();  // B1

  f32x4 zero = {0.f, 0.f, 0.f, 0.f};
  // ---- S = Qg.Kg^T ----
  short8 aq[2];
#pragma unroll
  for (int ks = 0; ks < 2; ks++)
    aq[ks] = *(const short8*)&Qs[(wid * 16 + lm) * STR + ks * 32 + quad * 8];
  f32x4 accs[4];
#pragma unroll
  for (int j = 0; j < 4; j++) accs[j] = zero;
#pragma unroll
  for (int j = 0; j < 4; j++)
#pragma unroll
    for (int ks = 0; ks < 2; ks++) {
      short8 bk = *(const short8*)&Ks[(j * 16 + lm) * STR + ks * 32 + quad * 8];
      accs[j] = __builtin_amdgcn_mfma_f32_16x16x32_bf16(aq[ks], bk, accs[j], 0, 0, 0);
    }
  float rowpart[4] = {0.f, 0.f, 0.f, 0.f};
#pragma unroll
  for (int j = 0; j < 4; j++) {
    const int s = j * 16 + lm;
#pragma unroll
    for (int r = 0; r < 4; r++) {
      const int t = wid * 16 + quad * 4 + r;
      float v = (s <= t) ? accs[j][r] : 0.f;
      accs[j][r] = v;
      rowpart[r] += v;
    }
  }
#pragma unroll
  for (int msk = 1; msk < 16; msk <<= 1)
#pragma unroll
    for (int r = 0; r < 4; r++) rowpart[r] += __shfl_xor(rowpart[r], msk, 64);
  if (lm == 0)
#pragma unroll
    for (int r = 0; r < 4; r++) denp[wid * 16 + quad * 4 + r] = rowpart[r];
#pragma unroll
  for (int j = 0; j < 4; j++)
#pragma unroll
    for (int r = 0; r < 4; r++)
      SL[(wid * 16 + quad * 4 + r) * STR + j * 16 + lm] = f2b_bits(accs[j][r]);

  // ---- O1^T = P^T.Qg^T ----
  f32x4 acco[4];
#pragma unroll
  for (int j = 0; j < 4; j++) acco[j] = zero;
  short8 ap[2];
#pragma unroll
  for (int ks = 0; ks < 2; ks++)
    ap[ks] = *(const short8*)&Pt[(wid * 16 + lm) * STR + ks * 32 + quad * 8];
#pragma unroll
  for (int j = 0; j < 4; j++)
#pragma unroll
    for (int ks = 0; ks < 2; ks++) {
      short8 bq = *(const short8*)&Qs[(j * 16 + lm) * STR + ks * 32 + quad * 8];
      acco[j] = __builtin_amdgcn_mfma_f32_16x16x32_bf16(ap[ks], bq, acco[j], 0, 0, 0);
    }
  __syncthreads();  // B2: SL + denp complete

  if (tid < 64) {
    float s = 1e-5f + denp[tid];
    for (int d = 0; d < 64; d++) s += b2f(Qs[tid * STR + d]) * skp[d];
    invden[tid] = 1.f / s;
  }

  // ---- O2^T += V^T.S^T ----
  short8 av[2];
#pragma unroll
  for (int ks = 0; ks < 2; ks++)
    av[ks] = *(const short8*)&Vt[(wid * 16 + lm) * STR + ks * 32 + quad * 8];
#pragma unroll
  for (int j = 0; j < 4; j++)
#pragma unroll
    for (int ks = 0; ks < 2; ks++) {
      short8 bs = *(const short8*)&SL[(j * 16 + lm) * STR + ks * 32 + quad * 8];
      acco[j] = __builtin_amdgcn_mfma_f32_16x16x32_bf16(av[ks], bs, acco[j], 0, 0, 0);
    }
  __syncthreads();  // B3: invden ready

#pragma unroll
  for (int j = 0; j < 4; j++) {
    const int t = j * 16 + lm;
    const float idv = invden[t];
    short4v ov;
#pragma unroll
    for (int r = 0; r < 4; r++) ov[r] = f2b_bits(acco[j][r] * idv);
    *(short4v*)&((short*)O)[(size_t)(t0 + t) * DM + h * 64 + wid * 16 + quad * 4] = ov;
  }
}

// ---------------------------------------------------------------------------
// Proj GEMM: tile 64x64, BK=64, grid (16 n-fast, 32 m) = 512 blocks (2/CU).
// ---------------------------------------------------------------------------
__global__ __launch_bounds__(256) void gemm_proj(const bf16* __restrict__ A,
                                                 const bf16* __restrict__ W,
                                                 const float* __restrict__ bias,
                                                 float* __restrict__ Cout) {
  constexpr int K = 1024;
  __shared__ __align__(16) short As[2 * 64 * 32];
  __shared__ __align__(16) short Bs[2 * 64 * 32];

  const int tid = threadIdx.x;
  const int wid = tid >> 6, lane = tid & 63;
  const int wm = wid >> 1, wn = wid & 1;   // wave tile 32x32
  const int lm = lane & 15, quad = lane >> 4;

  const int n0 = blockIdx.x * 64;
  const int m0 = blockIdx.y * 64;
  const short* Ag = (const short*)A;
  const short* Wg = (const short*)W;

  f32x4 zero = {0.f, 0.f, 0.f, 0.f};
  f32x4 acc[2][2];
#pragma unroll
  for (int i = 0; i < 2; i++)
#pragma unroll
    for (int j = 0; j < 2; j++) acc[i][j] = zero;

  for (int kb = 0; kb < K; kb += 64) {
    __syncthreads();
#pragma unroll
    for (int sec = 0; sec < 2; sec++) {
      const int row = tid >> 2, seg = (tid & 3) * 8;
      gload16(&Ag[(size_t)(m0 + row) * K + kb + sec * 32 + seg],
              &As[sec * 2048 + wid * 512]);
      gload16(&Wg[(size_t)(n0 + row) * K + kb + sec * 32 + seg],
              &Bs[sec * 2048 + wid * 512]);
    }
    __syncthreads();
#pragma unroll
    for (int sec = 0; sec < 2; sec++) {
      short8 afr[2], bfr[2];
#pragma unroll
      for (int i = 0; i < 2; i++)
        afr[i] = *(const short8*)&As[sec * 2048 + (wm * 32 + i * 16 + lm) * 32 + quad * 8];
#pragma unroll
      for (int j = 0; j < 2; j++)
        bfr[j] = *(const short8*)&Bs[sec * 2048 + (wn * 32 + j * 16 + lm) * 32 + quad * 8];
#pragma unroll
      for (int i = 0; i < 2; i++)
#pragma unroll
        for (int j = 0; j < 2; j++)
          acc[i][j] = __builtin_amdgcn_mfma_f32_16x16x32_bf16(afr[i], bfr[j], acc[i][j], 0, 0, 0);
    }
  }
#pragma unroll
  for (int i = 0; i < 2; i++) {
    const int rbase = m0 + wm * 32 + i * 16 + quad * 4;
#pragma unroll
    for (int j = 0; j < 2; j++) {
      const int col = n0 + wn * 32 + j * 16 + lm;
      const float bval = bias[col];
#pragma unroll
      for (int r = 0; r < 4; r++)
        Cout[(size_t)(rbase + r) * DM + col] = acc[i][j][r] + bval;
    }
  }
}

// ---------------------------------------------------------------------------
extern "C" void kernel_launch(void* const* d_in, const int* in_sizes, int n_in,
                              void* d_out, int out_size, void* d_ws, size_t ws_size,
                              hipStream_t stream) {
  (void)in_sizes; (void)n_in; (void)out_size; (void)ws_size;
  const float* x      = (const float*)d_in[0];
  const float* ln_g   = (const float*)d_in[1];
  const float* ln_b   = (const float*)d_in[2];
  const float* qkv_w  = (const float*)d_in[3];
  const float* qkv_b  = (const float*)d_in[4];
  const float* gate_w = (const float*)d_in[5];
  const float* gate_b = (const float*)d_in[6];
  const float* proj_w = (const float*)d_in[7];
  const float* proj_b = (const float*)d_in[8];
  float* out = (float*)d_out;

  char* ws = (char*)d_ws;
  size_t off = 0;
  auto alloc = [&](size_t bytes) {
    void* p = ws + off;
    off += (bytes + 255) & ~(size_t)255;
    return p;
  };
  bf16*  xn       = (bf16*)alloc((size_t)T_SEQ * DM * 2);
  bf16*  xbf      = (bf16*)alloc((size_t)T_SEQ * DM * 2);
  bf16*  wqkv     = (bf16*)alloc((size_t)3 * DM * DM * 2);
  bf16*  wgate    = (bf16*)alloc((size_t)DM * DM * 2);
  bf16*  wproj    = (bf16*)alloc((size_t)DM * DM * 2);
  short* Gb       = (short*)alloc((size_t)T_SEQ * DM * 2);
  float* gate_accum = (float*)alloc((size_t)T_SEQ * 4);
  short* Qb       = (short*)alloc((size_t)T_SEQ * DM * 2);
  short* Kb       = (short*)alloc((size_t)T_SEQ * DM * 2);
  short* Vb       = (short*)alloc((size_t)T_SEQ * DM * 2);
  short* VbT      = (short*)alloc((size_t)T_SEQ * DM * 2);
  bf16*  Obuf     = (bf16*)alloc((size_t)T_SEQ * DM * 2);
  float* SkvT     = (float*)alloc((size_t)NH * NCHUNK * 4096 * 4);
  float* Sk       = (float*)alloc((size_t)NH * NCHUNK * 64 * 4);

  prep_kernel<<<T_SEQ + PREP_WBLOCKS, 256, 0, stream>>>(
      x, ln_g, ln_b, qkv_w, gate_w, proj_w, xn, xbf, wqkv, wgate, wproj, gate_accum);
  gemm_gateqkv<<<dim3(32, 32), 256, 0, stream>>>(xbf, xn, wgate, wqkv, gate_b, qkv_b,
                                                 Gb, gate_accum, Qb, Kb, Vb, VbT);
  chunk_sum_mm<<<NH * NCHUNK, 256, 0, stream>>>(Kb, Gb, gate_accum, Vb, SkvT, Sk);
  scan_excl<<<260, 256, 0, stream>>>(SkvT, Sk);
  attn_mfma<<<NH * NCHUNK, 256, 0, stream>>>(Qb, Kb, Gb, gate_accum, VbT, SkvT, Sk, Obuf);
  gemm_proj<<<dim3(16, 32), 256, 0, stream>>>(Obuf, wproj, proj_b, out);
}